// Round 6
// baseline (159.398 us; speedup 1.0000x reference)
//
#include <hip/hip_runtime.h>

// AttentionBlock: B=8, C=256, S=2048, H=4, DK=64
// prep(transpose+cast) -> QKV GEMM -> fused attention (LDS triple-buffered KV,
// counted-vmcnt pipeline) -> out GEMM + residual. fp16 storage, fp32 MFMA accum.
// Softmax: constant-shift exp2 (scale*log2e folded into Q, shift folded into MFMA C-init),
// denominator via ones-row MFMA (no cross-lane reduction needed).

typedef _Float16 f16;
typedef __attribute__((ext_vector_type(4))) float f32x4;
typedef __attribute__((ext_vector_type(8))) _Float16 h8;
typedef __attribute__((ext_vector_type(4))) _Float16 h4;
typedef __attribute__((ext_vector_type(2))) __fp16 fp16x2;
typedef __attribute__((ext_vector_type(4))) __fp16 fp16x4;

#define SS 2048
#define CC 256
#define BB 8
#define HH 4
#define DK 64
#define O3 768
#define NT64 32  // 32 tiles of 64 keys; tile = 4096 f16 (8KB) each for K and V
#define C1F 0.1803368801111204f   // 0.125 * log2(e)
#define C2L2 11.541560327111707f  // 8 * log2(e)

#define MFMA32(a, b, c) __builtin_amdgcn_mfma_f32_16x16x32_f16(a, b, c, 0, 0, 0)
#define MFMA16(a, b, c) __builtin_amdgcn_mfma_f32_16x16x16f16(a, b, c, 0, 0, 0)

__device__ __forceinline__ void async_ld16(const f16* g, f16* lds) {
  __builtin_amdgcn_global_load_lds(
      (const __attribute__((address_space(1))) unsigned int*)g,
      (__attribute__((address_space(3))) unsigned int*)lds, 16, 0, 0);
}

// ---------------- prep: xt[b][s][c] = (f16) x[b][c][s] ----------------
__global__ __launch_bounds__(256) void k_prep_x(const float* __restrict__ x,
                                                f16* __restrict__ xt) {
  __shared__ float tile[64][65];
  int b = blockIdx.z, c0 = blockIdx.y * 64, s0 = blockIdx.x * 64;
  int t = threadIdx.x;
#pragma unroll
  for (int it = 0; it < 16; ++it) {
    int idx = it * 256 + t;
    int cl = idx >> 6, sl = idx & 63;
    tile[cl][sl] = x[(size_t)(b * CC + c0 + cl) * SS + s0 + sl];
  }
  __syncthreads();
#pragma unroll
  for (int it = 0; it < 16; ++it) {
    int idx = it * 256 + t;
    int sl = idx >> 6, cl = idx & 63;
    xt[(size_t)(b * SS + s0 + sl) * CC + c0 + cl] = (f16)tile[cl][sl];
  }
}

__global__ __launch_bounds__(256) void k_cast2(const float* __restrict__ a, f16* __restrict__ da,
                                               int na, const float* __restrict__ b,
                                               f16* __restrict__ db, int nb) {
  int i = blockIdx.x * 256 + threadIdx.x;
  if (i < na) da[i] = (f16)a[i];
  int j = i - na;
  if (j >= 0 && j < nb) db[j] = (f16)b[j];
}

// ---------------- QKV GEMM ----------------
// q: row-major qh[bh][s][d], PRE-SCALED by C1F (scale*log2e).
// k: ksw[bh][tile64][2 subtiles][2048]: within subtile elem = kl*64 + (doff ^ ((kl&7)*8))
// v: vsw[bh][tile64][2 subtiles][2048]: within subtile elem = d*32 + (p^(d&3))*8 + o*4 + (kl&3)
//    where p=(kl&15)>>2, o=kl>>4  (keys pair-interleaved lo/hi 4-groups, 2-bit XOR swizzle)
__global__ __launch_bounds__(256) void k_qkv(const f16* __restrict__ xt,
                                             const f16* __restrict__ wp,
                                             const float* __restrict__ bp,
                                             f16* __restrict__ qh, f16* __restrict__ ksw,
                                             f16* __restrict__ vsw) {
  __shared__ f16 lt[4][16][72];
  int b = blockIdx.z;
  int o0 = blockIdx.y * 64;
  int w = threadIdx.x >> 6, l = threadIdx.x & 63;
  int s0 = blockIdx.x * 64 + w * 16;
  int lr = l & 15, lg = l >> 4;

  const f16* aptr = xt + (size_t)(b * SS + s0 + lr) * CC;
  const f16* bptr = wp + (size_t)(o0 + lr) * CC;
  f32x4 acc[4] = {};
#pragma unroll
  for (int kk = 0; kk < CC; kk += 32) {
    h8 af = *(const h8*)(aptr + kk + lg * 8);
#pragma unroll
    for (int n = 0; n < 4; ++n) {
      h8 bf = *(const h8*)(bptr + n * 16 * CC + kk + lg * 8);
      acc[n] = MFMA32(af, bf, acc[n]);
    }
  }
  int seg = (o0 >> 6) % 3;  // 0=q 1=k 2=v
  int h = o0 / 192;
  int bh = b * HH + h;
  float scl = (seg == 0) ? C1F : 1.0f;
#pragma unroll
  for (int n = 0; n < 4; ++n) {
    float bb = bp[o0 + n * 16 + lr];
#pragma unroll
    for (int r = 0; r < 4; ++r) acc[n][r] = (acc[n][r] + bb) * scl;
  }

  if (seg == 2) {
#pragma unroll
    for (int n = 0; n < 4; ++n) {
      int d = n * 16 + lr;
      int sg = s0 + lg * 4;
      int kl = sg & 31;
      int o = kl >> 4;
      int pp = (kl & 15) >> 2;
      int ps = pp ^ (d & 3);
      h4 pv;
#pragma unroll
      for (int r = 0; r < 4; ++r) pv[r] = (f16)acc[n][r];
      size_t elem = ((size_t)bh * NT64 + (sg >> 6)) * 4096 + ((sg >> 5) & 1) * 2048 +
                    d * 32 + ps * 8 + o * 4;
      *(h4*)(vsw + elem) = pv;
    }
  } else {
#pragma unroll
    for (int n = 0; n < 4; ++n)
#pragma unroll
      for (int r = 0; r < 4; ++r) lt[w][lg * 4 + r][n * 16 + lr] = (f16)acc[n][r];
    __syncthreads();
    int srow = l >> 2;
    int key_g = s0 + srow;
    const f16* srcr = &lt[w][srow][(l & 3) * 16];
    if (seg == 0) {
      f16* dst = qh + (size_t)(bh * SS + key_g) * DK + (l & 3) * 16;
      ((int4*)dst)[0] = ((const int4*)srcr)[0];
      ((int4*)dst)[1] = ((const int4*)srcr)[1];
    } else {
      int kl = key_g & 31;
      size_t tb = ((size_t)bh * NT64 + (key_g >> 6)) * 4096 + ((key_g >> 5) & 1) * 2048 +
                  (size_t)kl * 64;
      int swz = (kl & 7) << 3;
      int d0 = (l & 3) * 16;
      *(h8*)(ksw + tb + (d0 ^ swz)) = ((const h8*)srcr)[0];
      *(h8*)(ksw + tb + ((d0 + 8) ^ swz)) = ((const h8*)srcr)[1];
    }
  }
}

// ---------------- attention ----------------
// Block: 4 waves x 32 queries = 128 q. 64-key tiles TRIPLE-buffered in LDS
// (3x8KB K + 3x8KB V), staged via global_load_lds w=16, loads kept 2 tiles in
// flight with counted vmcnt(8) — never drained to 0 in the main loop (T4).
// Per iter: barrier A (buffer free) -> issue STAGE(t+2) -> vmcnt(8) (tile t's
// loads retired) -> barrier B -> compute tile t.
__global__ __launch_bounds__(256) void k_attn(const f16* __restrict__ qh,
                                              const f16* __restrict__ ksw,
                                              const f16* __restrict__ vsw,
                                              f16* __restrict__ res) {
  __shared__ f16 kbuf[3][4096];
  __shared__ f16 vbuf[3][4096];
  int id = blockIdx.x;
  int xcd = id & 7, slot = id >> 3;
  int bh = xcd * 4 + (slot >> 4);  // 4 heads per XCD -> K/V L2-resident
  int qt = slot & 15;
  int w = threadIdx.x >> 6, l = threadIdx.x & 63;
  int q0 = qt * 128 + w * 32;
  int lr = l & 15, lg = l >> 4;

  h8 qf[2][2];
#pragma unroll
  for (int t = 0; t < 2; ++t) {
    const f16* qp = qh + (size_t)(bh * SS + q0 + t * 16 + lr) * DK;
    qf[t][0] = *(const h8*)(qp + lg * 8);
    qf[t][1] = *(const h8*)(qp + 32 + lg * 8);
  }

  const f16* kg = ksw + (size_t)bh * (SS * DK);
  const f16* vg = vsw + (size_t)bh * (SS * DK);

#define STAGE(bufi, tile)                                          \
  {                                                                \
    const f16* kq = kg + (tile) * 4096 + w * 1024 + l * 8;         \
    const f16* vq = vg + (tile) * 4096 + w * 1024 + l * 8;         \
    async_ld16(kq, &kbuf[bufi][w * 1024 + l * 8]);                 \
    async_ld16(kq + 512, &kbuf[bufi][w * 1024 + 512 + l * 8]);     \
    async_ld16(vq, &vbuf[bufi][w * 1024 + l * 8]);                 \
    async_ld16(vq + 512, &vbuf[bufi][w * 1024 + 512 + l * 8]);     \
  }

  // fragment element offsets within a 2048-elem subtile
  int swk = (lr & 7) << 3;
  int ek[2][2];
#pragma unroll
  for (int kb = 0; kb < 2; ++kb)
#pragma unroll
    for (int ch = 0; ch < 2; ++ch)
      ek[kb][ch] = (lr + kb * 16) * 64 + ((ch * 32 + lg * 8) ^ swk);
  int ev = lr * 32 + ((lg ^ (lr & 3)) * 8);  // + m*512

  f32x4 oacc[2][4] = {};
  f32x4 dacc[2] = {};
  const f32x4 cinit = {-C2L2, -C2L2, -C2L2, -C2L2};
  const h4 ones = {(f16)1.0f, (f16)1.0f, (f16)1.0f, (f16)1.0f};

  // prologue: stage tiles 0 and 1 (8 loads outstanding)
  STAGE(0, 0);
  STAGE(1, 1);

  for (int kt = 0; kt < NT64; ++kt) {
    int cur = kt % 3;
    int nb = (kt + 2) % 3;
    int nxt = (kt + 2) & (NT64 - 1);
    __syncthreads();  // A: all waves done reading the buffer STAGE overwrites
    STAGE(nb, nxt);
    asm volatile("s_waitcnt vmcnt(8)" ::: "memory");  // tile kt's loads retired
    __syncthreads();  // B: every wave's tile-kt loads complete
    const f16* kb_ = kbuf[cur];
    const f16* vb_ = vbuf[cur];
#pragma unroll
    for (int sub = 0; sub < 2; ++sub) {
      int sb = sub * 2048;
      h8 kf[2][2];
#pragma unroll
      for (int kb = 0; kb < 2; ++kb)
#pragma unroll
        for (int ch = 0; ch < 2; ++ch) kf[kb][ch] = *(const h8*)&kb_[sb + ek[kb][ch]];
      h8 vv[4];
#pragma unroll
      for (int m = 0; m < 4; ++m) vv[m] = *(const h8*)&vb_[sb + ev + m * 512];

      __builtin_amdgcn_s_setprio(1);
      f32x4 sacc[2][2];
#pragma unroll
      for (int t = 0; t < 2; ++t)
#pragma unroll
        for (int kb = 0; kb < 2; ++kb) {
          sacc[t][kb] = MFMA32(kf[kb][0], qf[t][0], cinit);
          sacc[t][kb] = MFMA32(kf[kb][1], qf[t][1], sacc[t][kb]);
        }
      h4 pf[2][2];
#pragma unroll
      for (int t = 0; t < 2; ++t)
#pragma unroll
        for (int kb = 0; kb < 2; ++kb) {
          float e0 = exp2f(sacc[t][kb][0]);
          float e1 = exp2f(sacc[t][kb][1]);
          float e2 = exp2f(sacc[t][kb][2]);
          float e3 = exp2f(sacc[t][kb][3]);
          fp16x2 plo = __builtin_amdgcn_cvt_pkrtz(e0, e1);
          fp16x2 phi = __builtin_amdgcn_cvt_pkrtz(e2, e3);
          fp16x4 pc = __builtin_shufflevector(plo, phi, 0, 1, 2, 3);
          pf[t][kb] = __builtin_bit_cast(h4, pc);
        }
#pragma unroll
      for (int t = 0; t < 2; ++t) {
        dacc[t] = MFMA16(ones, pf[t][0], dacc[t]);
        dacc[t] = MFMA16(ones, pf[t][1], dacc[t]);
      }
#pragma unroll
      for (int t = 0; t < 2; ++t)
#pragma unroll
        for (int m = 0; m < 4; ++m) {
          h4 vlo = __builtin_shufflevector(vv[m], vv[m], 0, 1, 2, 3);
          h4 vhi = __builtin_shufflevector(vv[m], vv[m], 4, 5, 6, 7);
          oacc[t][m] = MFMA16(vlo, pf[t][0], oacc[t][m]);
          oacc[t][m] = MFMA16(vhi, pf[t][1], oacc[t][m]);
        }
      __builtin_amdgcn_s_setprio(0);
    }
  }

  int b = bh >> 2, h = bh & 3;
#pragma unroll
  for (int t = 0; t < 2; ++t) {
    float inv = 1.0f / dacc[t][0];  // every lane holds its own q-column's sum
    f16* rp = res + (size_t)(b * SS + q0 + t * 16 + lr) * CC + h * DK + lg * 4;
#pragma unroll
    for (int m = 0; m < 4; ++m) {
      h4 rv;
#pragma unroll
      for (int r = 0; r < 4; ++r) rv[r] = (f16)(oacc[t][m][r] * inv);
      *(h4*)(rp + m * 16) = rv;
    }
  }
}

// ---------------- out GEMM + bias + residual ----------------
__global__ __launch_bounds__(256) void k_out(const f16* __restrict__ res,
                                             const f16* __restrict__ wo,
                                             const float* __restrict__ bo,
                                             const float* __restrict__ x,
                                             float* __restrict__ out) {
  int b = blockIdx.z;
  int c0 = blockIdx.y * 64;
  int w = threadIdx.x >> 6, l = threadIdx.x & 63;
  int s0 = blockIdx.x * 64 + w * 16;
  int lr = l & 15, lg = l >> 4;

  const f16* aptr = res + (size_t)(b * SS + s0 + lr) * CC;
  const f16* bptr = wo + (size_t)(c0 + lr) * CC;
  f32x4 acc[4] = {};
#pragma unroll
  for (int kk = 0; kk < CC; kk += 32) {
    h8 af = *(const h8*)(aptr + kk + lg * 8);
#pragma unroll
    for (int n = 0; n < 4; ++n) {
      h8 bf = *(const h8*)(bptr + n * 16 * CC + kk + lg * 8);
      acc[n] = MFMA32(af, bf, acc[n]);
    }
  }
#pragma unroll
  for (int n = 0; n < 4; ++n) {
    int c = c0 + n * 16 + lr;
    float bb = bo[c];
    const float* xp = x + (size_t)(b * CC + c) * SS + s0 + lg * 4;
    float4 xv = *(const float4*)xp;
    float4 ov;
    ov.x = acc[n][0] + bb + xv.x;
    ov.y = acc[n][1] + bb + xv.y;
    ov.z = acc[n][2] + bb + xv.z;
    ov.w = acc[n][3] + bb + xv.w;
    *(float4*)(out + (size_t)(b * CC + c) * SS + s0 + lg * 4) = ov;
  }
}

extern "C" void kernel_launch(void* const* d_in, const int* in_sizes, int n_in,
                              void* d_out, int out_size, void* d_ws, size_t ws_size,
                              hipStream_t stream) {
  const float* x = (const float*)d_in[0];
  const float* w_proj = (const float*)d_in[1];
  const float* b_proj = (const float*)d_in[2];
  const float* w_out = (const float*)d_in[3];
  const float* b_out = (const float*)d_in[4];
  float* out = (float*)d_out;

  char* p = (char*)d_ws;
  f16* xt = (f16*)p; p += (size_t)BB * SS * CC * 2;
  f16* wp = (f16*)p; p += (size_t)O3 * CC * 2;
  f16* wo = (f16*)p; p += (size_t)CC * CC * 2;
  f16* qh = (f16*)p; p += (size_t)BB * HH * SS * DK * 2;
  f16* ksw = (f16*)p; p += (size_t)BB * HH * SS * DK * 2;
  f16* vsw = (f16*)p; p += (size_t)BB * HH * SS * DK * 2;
  f16* res = (f16*)p;

  k_prep_x<<<dim3(SS / 64, CC / 64, BB), 256, 0, stream>>>(x, xt);
  k_cast2<<<(O3 * CC + CC * CC + 255) / 256, 256, 0, stream>>>(w_proj, wp, O3 * CC,
                                                               w_out, wo, CC * CC);
  k_qkv<<<dim3(SS / 64, O3 / 64, BB), 256, 0, stream>>>(xt, wp, b_proj, qh, ksw, vsw);
  k_attn<<<dim3(512), 256, 0, stream>>>(qh, ksw, vsw, res);
  k_out<<<dim3(SS / 64, CC / 64, BB), 256, 0, stream>>>(res, wo, b_out, x, out);
}

// Round 7
// 147.022 us; speedup vs baseline: 1.0842x; 1.0842x over previous
//
#include <hip/hip_runtime.h>

// AttentionBlock: B=8, C=256, S=2048, H=4, DK=64
// prep(transpose+cast) -> QKV GEMM -> fused attention (LDS double-buffered KV,
// 2-wave blocks) -> out GEMM + residual. fp16 storage, fp32 MFMA accum.
// Softmax: constant-shift exp2 (scale*log2e folded into Q, shift folded into MFMA C-init),
// raw v_exp_f32, denominator via ones-row MFMA (no cross-lane reduction).

typedef _Float16 f16;
typedef __attribute__((ext_vector_type(4))) float f32x4;
typedef __attribute__((ext_vector_type(8))) _Float16 h8;
typedef __attribute__((ext_vector_type(4))) _Float16 h4;
typedef __attribute__((ext_vector_type(2))) __fp16 fp16x2;
typedef __attribute__((ext_vector_type(4))) __fp16 fp16x4;

#define SS 2048
#define CC 256
#define BB 8
#define HH 4
#define DK 64
#define O3 768
#define NT64 32  // 32 tiles of 64 keys; tile = 4096 f16 (8KB) each for K and V
#define C1F 0.1803368801111204f   // 0.125 * log2(e)
#define C2L2 11.541560327111707f  // 8 * log2(e)

#define MFMA32(a, b, c) __builtin_amdgcn_mfma_f32_16x16x32_f16(a, b, c, 0, 0, 0)
#define MFMA16(a, b, c) __builtin_amdgcn_mfma_f32_16x16x16f16(a, b, c, 0, 0, 0)

#if __has_builtin(__builtin_amdgcn_exp2f)
#define EXP2(x) __builtin_amdgcn_exp2f(x)  // raw v_exp_f32 (args in [-40,-3]: safe)
#else
#define EXP2(x) exp2f(x)
#endif

__device__ __forceinline__ void async_ld16(const f16* g, f16* lds) {
  __builtin_amdgcn_global_load_lds(
      (const __attribute__((address_space(1))) unsigned int*)g,
      (__attribute__((address_space(3))) unsigned int*)lds, 16, 0, 0);
}

// ---------------- prep: xt[b][s][c] = (f16) x[b][c][s] ----------------
__global__ __launch_bounds__(256) void k_prep_x(const float* __restrict__ x,
                                                f16* __restrict__ xt) {
  __shared__ float tile[64][65];
  int b = blockIdx.z, c0 = blockIdx.y * 64, s0 = blockIdx.x * 64;
  int t = threadIdx.x;
#pragma unroll
  for (int it = 0; it < 16; ++it) {
    int idx = it * 256 + t;
    int cl = idx >> 6, sl = idx & 63;
    tile[cl][sl] = x[(size_t)(b * CC + c0 + cl) * SS + s0 + sl];
  }
  __syncthreads();
#pragma unroll
  for (int it = 0; it < 16; ++it) {
    int idx = it * 256 + t;
    int sl = idx >> 6, cl = idx & 63;
    xt[(size_t)(b * SS + s0 + sl) * CC + c0 + cl] = (f16)tile[cl][sl];
  }
}

__global__ __launch_bounds__(256) void k_cast2(const float* __restrict__ a, f16* __restrict__ da,
                                               int na, const float* __restrict__ b,
                                               f16* __restrict__ db, int nb) {
  int i = blockIdx.x * 256 + threadIdx.x;
  if (i < na) da[i] = (f16)a[i];
  int j = i - na;
  if (j >= 0 && j < nb) db[j] = (f16)b[j];
}

// ---------------- QKV GEMM ----------------
// q: row-major qh[bh][s][d], PRE-SCALED by C1F (scale*log2e).
// k: ksw[bh][tile64][2 subtiles][2048]: within subtile elem = kl*64 + (doff ^ ((kl&7)*8))
// v: vsw[bh][tile64][2 subtiles][2048]: within subtile elem = d*32 + (p^((d>>1)&3))*8
//    + o*4 + (kl&3) where p=(kl&15)>>2, o=kl>>4  (swizzle uses d bits 1-2 so a
//    16-lane read phase collides only 2-way, which is free)
__global__ __launch_bounds__(256) void k_qkv(const f16* __restrict__ xt,
                                             const f16* __restrict__ wp,
                                             const float* __restrict__ bp,
                                             f16* __restrict__ qh, f16* __restrict__ ksw,
                                             f16* __restrict__ vsw) {
  __shared__ f16 lt[4][16][72];
  int b = blockIdx.z;
  int o0 = blockIdx.y * 64;
  int w = threadIdx.x >> 6, l = threadIdx.x & 63;
  int s0 = blockIdx.x * 64 + w * 16;
  int lr = l & 15, lg = l >> 4;

  const f16* aptr = xt + (size_t)(b * SS + s0 + lr) * CC;
  const f16* bptr = wp + (size_t)(o0 + lr) * CC;
  f32x4 acc[4] = {};
#pragma unroll
  for (int kk = 0; kk < CC; kk += 32) {
    h8 af = *(const h8*)(aptr + kk + lg * 8);
#pragma unroll
    for (int n = 0; n < 4; ++n) {
      h8 bf = *(const h8*)(bptr + n * 16 * CC + kk + lg * 8);
      acc[n] = MFMA32(af, bf, acc[n]);
    }
  }
  int seg = (o0 >> 6) % 3;  // 0=q 1=k 2=v
  int h = o0 / 192;
  int bh = b * HH + h;
  float scl = (seg == 0) ? C1F : 1.0f;
#pragma unroll
  for (int n = 0; n < 4; ++n) {
    float bb = bp[o0 + n * 16 + lr];
#pragma unroll
    for (int r = 0; r < 4; ++r) acc[n][r] = (acc[n][r] + bb) * scl;
  }

  if (seg == 2) {
#pragma unroll
    for (int n = 0; n < 4; ++n) {
      int d = n * 16 + lr;
      int sg = s0 + lg * 4;
      int kl = sg & 31;
      int o = kl >> 4;
      int pp = (kl & 15) >> 2;
      int ps = pp ^ ((d >> 1) & 3);
      h4 pv;
#pragma unroll
      for (int r = 0; r < 4; ++r) pv[r] = (f16)acc[n][r];
      size_t elem = ((size_t)bh * NT64 + (sg >> 6)) * 4096 + ((sg >> 5) & 1) * 2048 +
                    d * 32 + ps * 8 + o * 4;
      *(h4*)(vsw + elem) = pv;
    }
  } else {
#pragma unroll
    for (int n = 0; n < 4; ++n)
#pragma unroll
      for (int r = 0; r < 4; ++r) lt[w][lg * 4 + r][n * 16 + lr] = (f16)acc[n][r];
    __syncthreads();
    int srow = l >> 2;
    int key_g = s0 + srow;
    const f16* srcr = &lt[w][srow][(l & 3) * 16];
    if (seg == 0) {
      f16* dst = qh + (size_t)(bh * SS + key_g) * DK + (l & 3) * 16;
      ((int4*)dst)[0] = ((const int4*)srcr)[0];
      ((int4*)dst)[1] = ((const int4*)srcr)[1];
    } else {
      int kl = key_g & 31;
      size_t tb = ((size_t)bh * NT64 + (key_g >> 6)) * 4096 + ((key_g >> 5) & 1) * 2048 +
                  (size_t)kl * 64;
      int swz = (kl & 7) << 3;
      int d0 = (l & 3) * 16;
      *(h8*)(ksw + tb + (d0 ^ swz)) = ((const h8*)srcr)[0];
      *(h8*)(ksw + tb + ((d0 + 8) ^ swz)) = ((const h8*)srcr)[1];
    }
  }
}

// ---------------- attention ----------------
// Block: 2 waves x 32 queries = 64 q; 1024 blocks = 4/CU (de-lockstepped sync
// domains at same total wave count). 64-key tiles double-buffered in LDS
// (8KB K + 8KB V per buf), staged via global_load_lds w=16, shared by both waves.
// Schedule per iter: STAGE(t+1) -> compute(t) -> vmcnt(0) -> barrier (T3 2-phase:
// tile t+1's latency hides under compute(t)).
// S^T = mfma32(K, Qscaled) with C-init = -8*log2e. P = exp2(sacc) via v_exp_f32.
// Denominator: dacc = mfma16(ones, P) -> every lane holds its q's sum.
__global__ __launch_bounds__(128) void k_attn(const f16* __restrict__ qh,
                                              const f16* __restrict__ ksw,
                                              const f16* __restrict__ vsw,
                                              f16* __restrict__ res) {
  __shared__ f16 kbuf[2][4096];
  __shared__ f16 vbuf[2][4096];
  int id = blockIdx.x;
  int xcd = id & 7, slot = id >> 3;  // 128 slots per XCD
  int bh = xcd * 4 + (slot >> 5);    // 4 heads per XCD -> K/V L2-resident
  int qt = slot & 31;
  int w = threadIdx.x >> 6, l = threadIdx.x & 63;
  int q0 = qt * 64 + w * 32;
  int lr = l & 15, lg = l >> 4;

  h8 qf[2][2];
#pragma unroll
  for (int t = 0; t < 2; ++t) {
    const f16* qp = qh + (size_t)(bh * SS + q0 + t * 16 + lr) * DK;
    qf[t][0] = *(const h8*)(qp + lg * 8);
    qf[t][1] = *(const h8*)(qp + 32 + lg * 8);
  }

  const f16* kg = ksw + (size_t)bh * (SS * DK);
  const f16* vg = vsw + (size_t)bh * (SS * DK);

#define STAGE(bufi, tile)                                           \
  {                                                                 \
    const f16* kq = kg + (size_t)(tile) * 4096 + w * 2048 + l * 8;  \
    const f16* vq = vg + (size_t)(tile) * 4096 + w * 2048 + l * 8;  \
    f16* kd = &kbuf[bufi][w * 2048];                                \
    f16* vd = &vbuf[bufi][w * 2048];                                \
    async_ld16(kq, kd);                                             \
    async_ld16(kq + 512, kd + 512);                                 \
    async_ld16(kq + 1024, kd + 1024);                               \
    async_ld16(kq + 1536, kd + 1536);                               \
    async_ld16(vq, vd);                                             \
    async_ld16(vq + 512, vd + 512);                                 \
    async_ld16(vq + 1024, vd + 1024);                               \
    async_ld16(vq + 1536, vd + 1536);                               \
  }

  // fragment element offsets within a 2048-elem subtile
  int swk = (lr & 7) << 3;
  int ek[2][2];
#pragma unroll
  for (int kb = 0; kb < 2; ++kb)
#pragma unroll
    for (int ch = 0; ch < 2; ++ch)
      ek[kb][ch] = (lr + kb * 16) * 64 + ((ch * 32 + lg * 8) ^ swk);
  int ev = lr * 32 + ((lg ^ ((lr >> 1) & 3)) * 8);  // + m*512

  STAGE(0, 0);
  asm volatile("s_waitcnt vmcnt(0)" ::: "memory");
  __syncthreads();

  f32x4 oacc[2][4] = {};
  f32x4 dacc[2] = {};
  const f32x4 cinit = {-C2L2, -C2L2, -C2L2, -C2L2};
  const h4 ones = {(f16)1.0f, (f16)1.0f, (f16)1.0f, (f16)1.0f};

  for (int kt = 0; kt < NT64; ++kt) {
    int cur = kt & 1;
    int nxt = (kt + 1) & (NT64 - 1);
    STAGE(cur ^ 1, nxt);

    const f16* kb_ = kbuf[cur];
    const f16* vb_ = vbuf[cur];
#pragma unroll
    for (int sub = 0; sub < 2; ++sub) {
      int sb = sub * 2048;
      h8 kf[2][2];
#pragma unroll
      for (int kb = 0; kb < 2; ++kb)
#pragma unroll
        for (int ch = 0; ch < 2; ++ch) kf[kb][ch] = *(const h8*)&kb_[sb + ek[kb][ch]];
      h8 vv[4];
#pragma unroll
      for (int m = 0; m < 4; ++m) vv[m] = *(const h8*)&vb_[sb + ev + m * 512];

      __builtin_amdgcn_s_setprio(1);
      f32x4 sacc[2][2];
#pragma unroll
      for (int t = 0; t < 2; ++t)
#pragma unroll
        for (int kb = 0; kb < 2; ++kb) {
          sacc[t][kb] = MFMA32(kf[kb][0], qf[t][0], cinit);
          sacc[t][kb] = MFMA32(kf[kb][1], qf[t][1], sacc[t][kb]);
        }
      h4 pf[2][2];
#pragma unroll
      for (int t = 0; t < 2; ++t)
#pragma unroll
        for (int kb = 0; kb < 2; ++kb) {
          float e0 = EXP2(sacc[t][kb][0]);
          float e1 = EXP2(sacc[t][kb][1]);
          float e2 = EXP2(sacc[t][kb][2]);
          float e3 = EXP2(sacc[t][kb][3]);
          fp16x2 plo = __builtin_amdgcn_cvt_pkrtz(e0, e1);
          fp16x2 phi = __builtin_amdgcn_cvt_pkrtz(e2, e3);
          fp16x4 pc = __builtin_shufflevector(plo, phi, 0, 1, 2, 3);
          pf[t][kb] = __builtin_bit_cast(h4, pc);
        }
#pragma unroll
      for (int t = 0; t < 2; ++t) {
        dacc[t] = MFMA16(ones, pf[t][0], dacc[t]);
        dacc[t] = MFMA16(ones, pf[t][1], dacc[t]);
      }
#pragma unroll
      for (int t = 0; t < 2; ++t)
#pragma unroll
        for (int m = 0; m < 4; ++m) {
          h4 vlo = __builtin_shufflevector(vv[m], vv[m], 0, 1, 2, 3);
          h4 vhi = __builtin_shufflevector(vv[m], vv[m], 4, 5, 6, 7);
          oacc[t][m] = MFMA16(vlo, pf[t][0], oacc[t][m]);
          oacc[t][m] = MFMA16(vhi, pf[t][1], oacc[t][m]);
        }
      __builtin_amdgcn_s_setprio(0);
    }
    asm volatile("s_waitcnt vmcnt(0)" ::: "memory");
    __syncthreads();
  }

  int b = bh >> 2, h = bh & 3;
#pragma unroll
  for (int t = 0; t < 2; ++t) {
    float inv = 1.0f / dacc[t][0];  // every lane holds its own q-column's sum
    f16* rp = res + (size_t)(b * SS + q0 + t * 16 + lr) * CC + h * DK + lg * 4;
#pragma unroll
    for (int m = 0; m < 4; ++m) {
      h4 rv;
#pragma unroll
      for (int r = 0; r < 4; ++r) rv[r] = (f16)(oacc[t][m][r] * inv);
      *(h4*)(rp + m * 16) = rv;
    }
  }
}

// ---------------- out GEMM + bias + residual ----------------
__global__ __launch_bounds__(256) void k_out(const f16* __restrict__ res,
                                             const f16* __restrict__ wo,
                                             const float* __restrict__ bo,
                                             const float* __restrict__ x,
                                             float* __restrict__ out) {
  int b = blockIdx.z;
  int c0 = blockIdx.y * 64;
  int w = threadIdx.x >> 6, l = threadIdx.x & 63;
  int s0 = blockIdx.x * 64 + w * 16;
  int lr = l & 15, lg = l >> 4;

  const f16* aptr = res + (size_t)(b * SS + s0 + lr) * CC;
  const f16* bptr = wo + (size_t)(c0 + lr) * CC;
  f32x4 acc[4] = {};
#pragma unroll
  for (int kk = 0; kk < CC; kk += 32) {
    h8 af = *(const h8*)(aptr + kk + lg * 8);
#pragma unroll
    for (int n = 0; n < 4; ++n) {
      h8 bf = *(const h8*)(bptr + n * 16 * CC + kk + lg * 8);
      acc[n] = MFMA32(af, bf, acc[n]);
    }
  }
#pragma unroll
  for (int n = 0; n < 4; ++n) {
    int c = c0 + n * 16 + lr;
    float bb = bo[c];
    const float* xp = x + (size_t)(b * CC + c) * SS + s0 + lg * 4;
    float4 xv = *(const float4*)xp;
    float4 ov;
    ov.x = acc[n][0] + bb + xv.x;
    ov.y = acc[n][1] + bb + xv.y;
    ov.z = acc[n][2] + bb + xv.z;
    ov.w = acc[n][3] + bb + xv.w;
    *(float4*)(out + (size_t)(b * CC + c) * SS + s0 + lg * 4) = ov;
  }
}

extern "C" void kernel_launch(void* const* d_in, const int* in_sizes, int n_in,
                              void* d_out, int out_size, void* d_ws, size_t ws_size,
                              hipStream_t stream) {
  const float* x = (const float*)d_in[0];
  const float* w_proj = (const float*)d_in[1];
  const float* b_proj = (const float*)d_in[2];
  const float* w_out = (const float*)d_in[3];
  const float* b_out = (const float*)d_in[4];
  float* out = (float*)d_out;

  char* p = (char*)d_ws;
  f16* xt = (f16*)p; p += (size_t)BB * SS * CC * 2;
  f16* wp = (f16*)p; p += (size_t)O3 * CC * 2;
  f16* wo = (f16*)p; p += (size_t)CC * CC * 2;
  f16* qh = (f16*)p; p += (size_t)BB * HH * SS * DK * 2;
  f16* ksw = (f16*)p; p += (size_t)BB * HH * SS * DK * 2;
  f16* vsw = (f16*)p; p += (size_t)BB * HH * SS * DK * 2;
  f16* res = (f16*)p;

  k_prep_x<<<dim3(SS / 64, CC / 64, BB), 256, 0, stream>>>(x, xt);
  k_cast2<<<(O3 * CC + CC * CC + 255) / 256, 256, 0, stream>>>(w_proj, wp, O3 * CC,
                                                               w_out, wo, CC * CC);
  k_qkv<<<dim3(SS / 64, O3 / 64, BB), 256, 0, stream>>>(xt, wp, b_proj, qh, ksw, vsw);
  k_attn<<<dim3(1024), 128, 0, stream>>>(qh, ksw, vsw, res);
  k_out<<<dim3(SS / 64, CC / 64, BB), 256, 0, stream>>>(res, wo, b_out, x, out);
}

// Round 8
// 145.012 us; speedup vs baseline: 1.0992x; 1.0139x over previous
//
#include <hip/hip_runtime.h>

// AttentionBlock: B=8, C=256, S=2048, H=4, DK=64
// fused transpose+QKV GEMM (register-A) -> fused attention (LDS double-buffered KV,
// 2-wave blocks) -> out GEMM + residual. fp16 storage, fp32 MFMA accum.
// Softmax: constant-shift exp2 (scale*log2e folded into Q, shift folded into MFMA C-init),
// raw v_exp_f32, denominator via ones-row MFMA (no cross-lane reduction).

typedef _Float16 f16;
typedef __attribute__((ext_vector_type(4))) float f32x4;
typedef __attribute__((ext_vector_type(8))) _Float16 h8;
typedef __attribute__((ext_vector_type(4))) _Float16 h4;
typedef __attribute__((ext_vector_type(2))) __fp16 fp16x2;
typedef __attribute__((ext_vector_type(4))) __fp16 fp16x4;

#define SS 2048
#define CC 256
#define BB 8
#define HH 4
#define DK 64
#define O3 768
#define NT64 32  // 32 tiles of 64 keys; tile = 4096 f16 (8KB) each for K and V
#define C1F 0.1803368801111204f   // 0.125 * log2(e)
#define C2L2 11.541560327111707f  // 8 * log2(e)

#define MFMA32(a, b, c) __builtin_amdgcn_mfma_f32_16x16x32_f16(a, b, c, 0, 0, 0)
#define MFMA16(a, b, c) __builtin_amdgcn_mfma_f32_16x16x16f16(a, b, c, 0, 0, 0)

#if __has_builtin(__builtin_amdgcn_exp2f)
#define EXP2(x) __builtin_amdgcn_exp2f(x)  // raw v_exp_f32 (args in [-40,-3]: safe)
#else
#define EXP2(x) exp2f(x)
#endif

__device__ __forceinline__ void async_ld16(const f16* g, f16* lds) {
  __builtin_amdgcn_global_load_lds(
      (const __attribute__((address_space(1))) unsigned int*)g,
      (__attribute__((address_space(3))) unsigned int*)lds, 16, 0, 0);
}

__global__ __launch_bounds__(256) void k_cast2(const float* __restrict__ a, f16* __restrict__ da,
                                               int na, const float* __restrict__ b,
                                               f16* __restrict__ db, int nb) {
  int i = blockIdx.x * 256 + threadIdx.x;
  if (i < na) da[i] = (f16)a[i];
  int j = i - na;
  if (j >= 0 && j < nb) db[j] = (f16)b[j];
}

// ---------------- fused transpose + QKV GEMM ----------------
// Grid (32 s-tiles, 8 b), 512 threads = 8 waves. Wave w: row-group wq=w&3 (16 s-rows),
// o-half p=w>>2 (32 of 64 o-cols). Phase 1: stage x[b][c][s0..+63] through LDS f32
// transpose chunks; each wave keeps its full A-operand (16 rows x 256 k) in 8 h8 regs.
// Phase 2: 12 o-tiles; B-frags from global (w_proj, L2-hot); epilogue as before:
//   q: row-major qh[bh][s][d], PRE-SCALED by C1F
//   k: ksw subtile elem = kl*64 + (doff ^ ((kl&7)*8))
//   v: vsw subtile elem = d*32 + (p^((d>>1)&3))*8 + o*4 + (kl&3)
__global__ __launch_bounds__(512) void k_qkvf(const float* __restrict__ x,
                                              const f16* __restrict__ wp,
                                              const float* __restrict__ bp,
                                              f16* __restrict__ qh, f16* __restrict__ ksw,
                                              f16* __restrict__ vsw) {
  __shared__ float ftile[64][69];   // pad 69: frag reads <=2-way bank conflicts
  __shared__ f16 lt2[8][16][40];    // wave-private q/k transpose staging
  int b = blockIdx.y;
  int s0 = blockIdx.x * 64;
  int tid = threadIdx.x;
  int w = tid >> 6, l = tid & 63;
  int lr = l & 15, lg = l >> 4;
  int p = w >> 2;   // o-col half
  int wq = w & 3;   // 16-row group
  int srow = wq * 16 + lr;

  // Phase 1: A into registers (16 rows x 256 k per wave)
  h8 af[8];
  for (int cc = 0; cc < CC; cc += 64) {
    __syncthreads();  // prev chunk fully read
#pragma unroll
    for (int it = 0; it < 2; ++it) {
      int idx = it * 512 + tid;
      int cl = idx >> 4, sl = (idx & 15) * 4;
      float4 v = *(const float4*)&x[(size_t)(b * CC + cc + cl) * SS + s0 + sl];
      ftile[cl][sl] = v.x;
      ftile[cl][sl + 1] = v.y;
      ftile[cl][sl + 2] = v.z;
      ftile[cl][sl + 3] = v.w;
    }
    __syncthreads();
#pragma unroll
    for (int j = 0; j < 2; ++j) {
      h8 v;
#pragma unroll
      for (int e = 0; e < 8; ++e) v[e] = (f16)ftile[j * 32 + lg * 8 + e][srow];
      af[(cc >> 5) + j] = v;
    }
  }

  // Phase 2: 12 o-tiles of 64
  for (int ot = 0; ot < 12; ++ot) {
    int o0 = ot * 64;
    int seg = ot % 3;  // 0=q 1=k 2=v
    int h = ot / 3;
    int bh = b * HH + h;
    f32x4 acc[2] = {};
#pragma unroll
    for (int nn = 0; nn < 2; ++nn) {
      int n = p * 2 + nn;
      const f16* bptr = wp + (size_t)(o0 + n * 16 + lr) * CC + lg * 8;
#pragma unroll
      for (int kk = 0; kk < 8; ++kk)
        acc[nn] = MFMA32(af[kk], *(const h8*)(bptr + kk * 32), acc[nn]);
    }
    float scl = (seg == 0) ? C1F : 1.0f;
#pragma unroll
    for (int nn = 0; nn < 2; ++nn) {
      float bb = bp[o0 + (p * 2 + nn) * 16 + lr];
#pragma unroll
      for (int r = 0; r < 4; ++r) acc[nn][r] = (acc[nn][r] + bb) * scl;
    }

    if (seg == 2) {
#pragma unroll
      for (int nn = 0; nn < 2; ++nn) {
        int d = (p * 2 + nn) * 16 + lr;
        int sg = s0 + wq * 16 + lg * 4;
        int kl = sg & 31;
        int o = kl >> 4;
        int pp = (kl & 15) >> 2;
        int ps = pp ^ ((d >> 1) & 3);
        h4 pv;
#pragma unroll
        for (int r = 0; r < 4; ++r) pv[r] = (f16)acc[nn][r];
        size_t elem = ((size_t)bh * NT64 + (sg >> 6)) * 4096 + ((sg >> 5) & 1) * 2048 +
                      d * 32 + ps * 8 + o * 4;
        *(h4*)(vsw + elem) = pv;
      }
    } else {
      // wave-private transpose: D-layout (row=s, col=o) -> row-major 16B stores
#pragma unroll
      for (int nn = 0; nn < 2; ++nn)
#pragma unroll
        for (int r = 0; r < 4; ++r) lt2[w][lg * 4 + r][nn * 16 + lr] = (f16)acc[nn][r];
      int rrow = l >> 2, cg = (l & 3) * 8;
      const f16* srcr = &lt2[w][rrow][cg];
      int s = s0 + wq * 16 + rrow;
      int dcol = p * 32 + cg;
      if (seg == 0) {
        *(int4*)(qh + (size_t)(bh * SS + s) * DK + dcol) = *(const int4*)srcr;
      } else {
        int kl = s & 31;
        size_t tb = ((size_t)bh * NT64 + (s >> 6)) * 4096 + ((s >> 5) & 1) * 2048 +
                    (size_t)kl * 64;
        int swz = (kl & 7) << 3;
        *(h8*)(ksw + tb + (dcol ^ swz)) = *(const h8*)srcr;
      }
    }
  }
}

// ---------------- attention ----------------
// Block: 2 waves x 32 queries = 64 q; 1024 blocks = 4/CU. 64-key tiles double-buffered
// in LDS (8KB K + 8KB V per buf), staged via global_load_lds w=16, shared by both waves.
// S^T = mfma32(K, Qscaled) with C-init = -8*log2e. P = exp2(sacc) via v_exp_f32.
// Denominator: dacc = mfma16(ones, P) -> every lane holds its q's sum.
__global__ __launch_bounds__(128) void k_attn(const f16* __restrict__ qh,
                                              const f16* __restrict__ ksw,
                                              const f16* __restrict__ vsw,
                                              f16* __restrict__ res) {
  __shared__ f16 kbuf[2][4096];
  __shared__ f16 vbuf[2][4096];
  int id = blockIdx.x;
  int xcd = id & 7, slot = id >> 3;  // 128 slots per XCD
  int bh = xcd * 4 + (slot >> 5);    // 4 heads per XCD -> K/V L2-resident
  int qt = slot & 31;
  int w = threadIdx.x >> 6, l = threadIdx.x & 63;
  int q0 = qt * 64 + w * 32;
  int lr = l & 15, lg = l >> 4;

  h8 qf[2][2];
#pragma unroll
  for (int t = 0; t < 2; ++t) {
    const f16* qp = qh + (size_t)(bh * SS + q0 + t * 16 + lr) * DK;
    qf[t][0] = *(const h8*)(qp + lg * 8);
    qf[t][1] = *(const h8*)(qp + 32 + lg * 8);
  }

  const f16* kg = ksw + (size_t)bh * (SS * DK);
  const f16* vg = vsw + (size_t)bh * (SS * DK);

#define STAGE(bufi, tile)                                           \
  {                                                                 \
    const f16* kq = kg + (size_t)(tile) * 4096 + w * 2048 + l * 8;  \
    const f16* vq = vg + (size_t)(tile) * 4096 + w * 2048 + l * 8;  \
    f16* kd = &kbuf[bufi][w * 2048];                                \
    f16* vd = &vbuf[bufi][w * 2048];                                \
    async_ld16(kq, kd);                                             \
    async_ld16(kq + 512, kd + 512);                                 \
    async_ld16(kq + 1024, kd + 1024);                               \
    async_ld16(kq + 1536, kd + 1536);                               \
    async_ld16(vq, vd);                                             \
    async_ld16(vq + 512, vd + 512);                                 \
    async_ld16(vq + 1024, vd + 1024);                               \
    async_ld16(vq + 1536, vd + 1536);                               \
  }

  // fragment element offsets within a 2048-elem subtile
  int swk = (lr & 7) << 3;
  int ek[2][2];
#pragma unroll
  for (int kb = 0; kb < 2; ++kb)
#pragma unroll
    for (int ch = 0; ch < 2; ++ch)
      ek[kb][ch] = (lr + kb * 16) * 64 + ((ch * 32 + lg * 8) ^ swk);
  int ev = lr * 32 + ((lg ^ ((lr >> 1) & 3)) * 8);  // + m*512

  STAGE(0, 0);
  asm volatile("s_waitcnt vmcnt(0)" ::: "memory");
  __syncthreads();

  f32x4 oacc[2][4] = {};
  f32x4 dacc[2] = {};
  const f32x4 cinit = {-C2L2, -C2L2, -C2L2, -C2L2};
  const h4 ones = {(f16)1.0f, (f16)1.0f, (f16)1.0f, (f16)1.0f};

  for (int kt = 0; kt < NT64; ++kt) {
    int cur = kt & 1;
    int nxt = (kt + 1) & (NT64 - 1);
    STAGE(cur ^ 1, nxt);

    const f16* kb_ = kbuf[cur];
    const f16* vb_ = vbuf[cur];
#pragma unroll
    for (int sub = 0; sub < 2; ++sub) {
      int sb = sub * 2048;
      h8 kf[2][2];
#pragma unroll
      for (int kb = 0; kb < 2; ++kb)
#pragma unroll
        for (int ch = 0; ch < 2; ++ch) kf[kb][ch] = *(const h8*)&kb_[sb + ek[kb][ch]];
      h8 vv[4];
#pragma unroll
      for (int m = 0; m < 4; ++m) vv[m] = *(const h8*)&vb_[sb + ev + m * 512];

      __builtin_amdgcn_s_setprio(1);
      f32x4 sacc[2][2];
#pragma unroll
      for (int t = 0; t < 2; ++t)
#pragma unroll
        for (int kb = 0; kb < 2; ++kb) {
          sacc[t][kb] = MFMA32(kf[kb][0], qf[t][0], cinit);
          sacc[t][kb] = MFMA32(kf[kb][1], qf[t][1], sacc[t][kb]);
        }
      h4 pf[2][2];
#pragma unroll
      for (int t = 0; t < 2; ++t)
#pragma unroll
        for (int kb = 0; kb < 2; ++kb) {
          float e0 = EXP2(sacc[t][kb][0]);
          float e1 = EXP2(sacc[t][kb][1]);
          float e2 = EXP2(sacc[t][kb][2]);
          float e3 = EXP2(sacc[t][kb][3]);
          fp16x2 plo = __builtin_amdgcn_cvt_pkrtz(e0, e1);
          fp16x2 phi = __builtin_amdgcn_cvt_pkrtz(e2, e3);
          fp16x4 pc = __builtin_shufflevector(plo, phi, 0, 1, 2, 3);
          pf[t][kb] = __builtin_bit_cast(h4, pc);
        }
#pragma unroll
      for (int t = 0; t < 2; ++t) {
        dacc[t] = MFMA16(ones, pf[t][0], dacc[t]);
        dacc[t] = MFMA16(ones, pf[t][1], dacc[t]);
      }
#pragma unroll
      for (int t = 0; t < 2; ++t)
#pragma unroll
        for (int m = 0; m < 4; ++m) {
          h4 vlo = __builtin_shufflevector(vv[m], vv[m], 0, 1, 2, 3);
          h4 vhi = __builtin_shufflevector(vv[m], vv[m], 4, 5, 6, 7);
          oacc[t][m] = MFMA16(vlo, pf[t][0], oacc[t][m]);
          oacc[t][m] = MFMA16(vhi, pf[t][1], oacc[t][m]);
        }
      __builtin_amdgcn_s_setprio(0);
    }
    asm volatile("s_waitcnt vmcnt(0)" ::: "memory");
    __syncthreads();
  }

  int b = bh >> 2, h = bh & 3;
#pragma unroll
  for (int t = 0; t < 2; ++t) {
    float inv = 1.0f / dacc[t][0];  // every lane holds its own q-column's sum
    f16* rp = res + (size_t)(b * SS + q0 + t * 16 + lr) * CC + h * DK + lg * 4;
#pragma unroll
    for (int m = 0; m < 4; ++m) {
      h4 rv;
#pragma unroll
      for (int r = 0; r < 4; ++r) rv[r] = (f16)(oacc[t][m][r] * inv);
      *(h4*)(rp + m * 16) = rv;
    }
  }
}

// ---------------- out GEMM + bias + residual ----------------
__global__ __launch_bounds__(256) void k_out(const f16* __restrict__ res,
                                             const f16* __restrict__ wo,
                                             const float* __restrict__ bo,
                                             const float* __restrict__ x,
                                             float* __restrict__ out) {
  int b = blockIdx.z;
  int c0 = blockIdx.y * 64;
  int w = threadIdx.x >> 6, l = threadIdx.x & 63;
  int s0 = blockIdx.x * 64 + w * 16;
  int lr = l & 15, lg = l >> 4;

  const f16* aptr = res + (size_t)(b * SS + s0 + lr) * CC;
  const f16* bptr = wo + (size_t)(c0 + lr) * CC;
  f32x4 acc[4] = {};
#pragma unroll
  for (int kk = 0; kk < CC; kk += 32) {
    h8 af = *(const h8*)(aptr + kk + lg * 8);
#pragma unroll
    for (int n = 0; n < 4; ++n) {
      h8 bf = *(const h8*)(bptr + n * 16 * CC + kk + lg * 8);
      acc[n] = MFMA32(af, bf, acc[n]);
    }
  }
#pragma unroll
  for (int n = 0; n < 4; ++n) {
    int c = c0 + n * 16 + lr;
    float bb = bo[c];
    const float* xp = x + (size_t)(b * CC + c) * SS + s0 + lg * 4;
    float4 xv = *(const float4*)xp;
    float4 ov;
    ov.x = acc[n][0] + bb + xv.x;
    ov.y = acc[n][1] + bb + xv.y;
    ov.z = acc[n][2] + bb + xv.z;
    ov.w = acc[n][3] + bb + xv.w;
    *(float4*)(out + (size_t)(b * CC + c) * SS + s0 + lg * 4) = ov;
  }
}

extern "C" void kernel_launch(void* const* d_in, const int* in_sizes, int n_in,
                              void* d_out, int out_size, void* d_ws, size_t ws_size,
                              hipStream_t stream) {
  const float* x = (const float*)d_in[0];
  const float* w_proj = (const float*)d_in[1];
  const float* b_proj = (const float*)d_in[2];
  const float* w_out = (const float*)d_in[3];
  const float* b_out = (const float*)d_in[4];
  float* out = (float*)d_out;

  char* p = (char*)d_ws;
  f16* wp = (f16*)p; p += (size_t)O3 * CC * 2;
  f16* wo = (f16*)p; p += (size_t)CC * CC * 2;
  f16* qh = (f16*)p; p += (size_t)BB * HH * SS * DK * 2;
  f16* ksw = (f16*)p; p += (size_t)BB * HH * SS * DK * 2;
  f16* vsw = (f16*)p; p += (size_t)BB * HH * SS * DK * 2;
  f16* res = (f16*)p;

  k_cast2<<<(O3 * CC + CC * CC + 255) / 256, 256, 0, stream>>>(w_proj, wp, O3 * CC,
                                                               w_out, wo, CC * CC);
  k_qkvf<<<dim3(SS / 64, BB), 512, 0, stream>>>(x, wp, b_proj, qh, ksw, vsw);
  k_attn<<<dim3(1024), 128, 0, stream>>>(qh, ksw, vsw, res);
  k_out<<<dim3(SS / 64, CC / 64, BB), 256, 0, stream>>>(res, wo, b_out, x, out);
}

// Round 9
// 137.728 us; speedup vs baseline: 1.1573x; 1.0529x over previous
//
#include <hip/hip_runtime.h>

// AttentionBlock: B=8, C=256, S=2048, H=4, DK=64
// fused transpose+QKV GEMM (register-A, 2 blocks/CU) -> fused attention (LDS
// double-buffered KV, 2-wave blocks, all-K=32 MFMAs) -> out GEMM + residual.
// fp16 storage, fp32 MFMA accum. Softmax: constant-shift exp2 (scale*log2e folded
// into Q, shift folded into MFMA C-init), raw v_exp_f32, denominator via ones-row
// MFMA. PV uses mfma_f32_16x16x32_f16 with a permuted-k convention: the MFMA k-index
// is abstract, so A(V) and B(P) just need the SAME key ordering per k-slot.

typedef _Float16 f16;
typedef __attribute__((ext_vector_type(4))) float f32x4;
typedef __attribute__((ext_vector_type(8))) _Float16 h8;
typedef __attribute__((ext_vector_type(4))) _Float16 h4;
typedef __attribute__((ext_vector_type(2))) __fp16 fp16x2;
typedef __attribute__((ext_vector_type(4))) __fp16 fp16x4;
typedef __attribute__((ext_vector_type(8))) __fp16 fp16x8;

#define SS 2048
#define CC 256
#define BB 8
#define HH 4
#define DK 64
#define O3 768
#define NT64 32  // 32 tiles of 64 keys; tile = 4096 f16 (8KB) each for K and V
#define C1F 0.1803368801111204f   // 0.125 * log2(e)
#define C2L2 11.541560327111707f  // 8 * log2(e)

#define MFMA32(a, b, c) __builtin_amdgcn_mfma_f32_16x16x32_f16(a, b, c, 0, 0, 0)

#if __has_builtin(__builtin_amdgcn_exp2f)
#define EXP2(x) __builtin_amdgcn_exp2f(x)  // raw v_exp_f32 (args in [-40,-3]: safe)
#else
#define EXP2(x) exp2f(x)
#endif

__device__ __forceinline__ void async_ld16(const f16* g, f16* lds) {
  __builtin_amdgcn_global_load_lds(
      (const __attribute__((address_space(1))) unsigned int*)g,
      (__attribute__((address_space(3))) unsigned int*)lds, 16, 0, 0);
}

__global__ __launch_bounds__(256) void k_cast2(const float* __restrict__ a, f16* __restrict__ da,
                                               int na, const float* __restrict__ b,
                                               f16* __restrict__ db, int nb) {
  int i = blockIdx.x * 256 + threadIdx.x;
  if (i < na) da[i] = (f16)a[i];
  int j = i - na;
  if (j >= 0 && j < nb) db[j] = (f16)b[j];
}

// ---------------- fused transpose + QKV GEMM ----------------
// Grid (64 s-tiles of 32, 8 b), 256 threads = 4 waves -> 2 blocks/CU. Wave w:
// row-group wq=w>>1 (16 s-rows), o-half p=w&1 (32 of 64 o-cols). Phase 1: stage
// x[b][c][s0..+31] through LDS f32 chunks; each wave keeps its full A-operand
// (16 rows x 256 k) in 8 h8 regs. Phase 2: 12 o-tiles; B-frags from global wp.
//   q: row-major qh[bh][s][d], PRE-SCALED by C1F
//   k: ksw subtile elem = kl*64 + (doff ^ ((kl&7)*8))
//   v: vsw subtile elem = d*32 + (pp^((d>>1)&3))*8 + o*4 + (kl&3)
__global__ __launch_bounds__(256) void k_qkvf(const float* __restrict__ x,
                                              const f16* __restrict__ wp,
                                              const float* __restrict__ bp,
                                              f16* __restrict__ qh, f16* __restrict__ ksw,
                                              f16* __restrict__ vsw) {
  __shared__ float ftile[64][33];   // [c-chunk][s], pad 33 (frag reads 2-way = free)
  __shared__ f16 lt2[4][16][40];    // wave-private q/k transpose staging
  int b = blockIdx.y;
  int s0 = blockIdx.x * 32;
  int tid = threadIdx.x;
  int w = tid >> 6, l = tid & 63;
  int lr = l & 15, lg = l >> 4;
  int p = w & 1;    // o-col half
  int wq = w >> 1;  // 16-row group
  int srow = wq * 16 + lr;

  // Phase 1: A into registers (16 rows x 256 k per wave)
  h8 af[8];
  for (int cc = 0; cc < CC; cc += 64) {
    __syncthreads();  // prev chunk fully read
#pragma unroll
    for (int it = 0; it < 2; ++it) {
      int idx = it * 256 + tid;
      int cl = idx >> 3, sl = (idx & 7) * 4;
      float4 v = *(const float4*)&x[(size_t)(b * CC + cc + cl) * SS + s0 + sl];
      ftile[cl][sl] = v.x;
      ftile[cl][sl + 1] = v.y;
      ftile[cl][sl + 2] = v.z;
      ftile[cl][sl + 3] = v.w;
    }
    __syncthreads();
#pragma unroll
    for (int j = 0; j < 2; ++j) {
      h8 v;
#pragma unroll
      for (int e = 0; e < 8; ++e) v[e] = (f16)ftile[j * 32 + lg * 8 + e][srow];
      af[(cc >> 5) + j] = v;
    }
  }

  // Phase 2: 12 o-tiles of 64
  for (int ot = 0; ot < 12; ++ot) {
    int o0 = ot * 64;
    int seg = ot % 3;  // 0=q 1=k 2=v
    int h = ot / 3;
    int bh = b * HH + h;
    f32x4 acc[2] = {};
#pragma unroll
    for (int nn = 0; nn < 2; ++nn) {
      int n = p * 2 + nn;
      const f16* bptr = wp + (size_t)(o0 + n * 16 + lr) * CC + lg * 8;
#pragma unroll
      for (int kk = 0; kk < 8; ++kk)
        acc[nn] = MFMA32(af[kk], *(const h8*)(bptr + kk * 32), acc[nn]);
    }
    float scl = (seg == 0) ? C1F : 1.0f;
#pragma unroll
    for (int nn = 0; nn < 2; ++nn) {
      float bb = bp[o0 + (p * 2 + nn) * 16 + lr];
#pragma unroll
      for (int r = 0; r < 4; ++r) acc[nn][r] = (acc[nn][r] + bb) * scl;
    }

    if (seg == 2) {
#pragma unroll
      for (int nn = 0; nn < 2; ++nn) {
        int d = (p * 2 + nn) * 16 + lr;
        int sg = s0 + wq * 16 + lg * 4;
        int kl = sg & 31;
        int o = kl >> 4;
        int pp = (kl & 15) >> 2;
        int ps = pp ^ ((d >> 1) & 3);
        h4 pv;
#pragma unroll
        for (int r = 0; r < 4; ++r) pv[r] = (f16)acc[nn][r];
        size_t elem = ((size_t)bh * NT64 + (sg >> 6)) * 4096 + ((sg >> 5) & 1) * 2048 +
                      d * 32 + ps * 8 + o * 4;
        *(h4*)(vsw + elem) = pv;
      }
    } else {
      // wave-private transpose: D-layout (row=s, col=o) -> row-major 16B stores
#pragma unroll
      for (int nn = 0; nn < 2; ++nn)
#pragma unroll
        for (int r = 0; r < 4; ++r) lt2[w][lg * 4 + r][nn * 16 + lr] = (f16)acc[nn][r];
      int rrow = l >> 2, cg = (l & 3) * 8;
      const f16* srcr = &lt2[w][rrow][cg];
      int s = s0 + wq * 16 + rrow;
      int dcol = p * 32 + cg;
      if (seg == 0) {
        *(int4*)(qh + (size_t)(bh * SS + s) * DK + dcol) = *(const int4*)srcr;
      } else {
        int kl = s & 31;
        size_t tb = ((size_t)bh * NT64 + (s >> 6)) * 4096 + ((s >> 5) & 1) * 2048 +
                    (size_t)kl * 64;
        int swz = (kl & 7) << 3;
        *(h8*)(ksw + tb + (dcol ^ swz)) = *(const h8*)srcr;
      }
    }
  }
}

// ---------------- attention ----------------
// Block: 2 waves x 32 queries = 64 q; 1024 blocks = 4/CU. 64-key tiles double-buffered
// in LDS (8KB K + 8KB V per buf), staged via global_load_lds w=16, shared by both waves.
// S^T = mfma32(K, Qscaled) with C-init = -8*log2e. P = exp2(sacc) via v_exp_f32.
// PV + denominator as K=32 MFMAs under the permuted-k convention:
//   kslot lg*8+e -> key (e<4 ? lg*4+e : 16+lg*4+e-4); vv[m] 8-group and
//   pf8 = [pf_kb0 | pf_kb1] both follow it, so O^T accumulates correctly.
__global__ __launch_bounds__(128) void k_attn(const f16* __restrict__ qh,
                                              const f16* __restrict__ ksw,
                                              const f16* __restrict__ vsw,
                                              f16* __restrict__ res) {
  __shared__ f16 kbuf[2][4096];
  __shared__ f16 vbuf[2][4096];
  int id = blockIdx.x;
  int xcd = id & 7, slot = id >> 3;  // 128 slots per XCD
  int bh = xcd * 4 + (slot >> 5);    // 4 heads per XCD -> K/V L2-resident
  int qt = slot & 31;
  int w = threadIdx.x >> 6, l = threadIdx.x & 63;
  int q0 = qt * 64 + w * 32;
  int lr = l & 15, lg = l >> 4;

  h8 qf[2][2];
#pragma unroll
  for (int t = 0; t < 2; ++t) {
    const f16* qp = qh + (size_t)(bh * SS + q0 + t * 16 + lr) * DK;
    qf[t][0] = *(const h8*)(qp + lg * 8);
    qf[t][1] = *(const h8*)(qp + 32 + lg * 8);
  }

  const f16* kg = ksw + (size_t)bh * (SS * DK);
  const f16* vg = vsw + (size_t)bh * (SS * DK);

#define STAGE(bufi, tile)                                           \
  {                                                                 \
    const f16* kq = kg + (size_t)(tile) * 4096 + w * 2048 + l * 8;  \
    const f16* vq = vg + (size_t)(tile) * 4096 + w * 2048 + l * 8;  \
    f16* kd = &kbuf[bufi][w * 2048];                                \
    f16* vd = &vbuf[bufi][w * 2048];                                \
    async_ld16(kq, kd);                                             \
    async_ld16(kq + 512, kd + 512);                                 \
    async_ld16(kq + 1024, kd + 1024);                               \
    async_ld16(kq + 1536, kd + 1536);                               \
    async_ld16(vq, vd);                                             \
    async_ld16(vq + 512, vd + 512);                                 \
    async_ld16(vq + 1024, vd + 1024);                               \
    async_ld16(vq + 1536, vd + 1536);                               \
  }

  // fragment element offsets within a 2048-elem subtile
  int swk = (lr & 7) << 3;
  int ek[2][2];
#pragma unroll
  for (int kb = 0; kb < 2; ++kb)
#pragma unroll
    for (int ch = 0; ch < 2; ++ch)
      ek[kb][ch] = (lr + kb * 16) * 64 + ((ch * 32 + lg * 8) ^ swk);
  int ev = lr * 32 + ((lg ^ ((lr >> 1) & 3)) * 8);  // + m*512

  STAGE(0, 0);
  asm volatile("s_waitcnt vmcnt(0)" ::: "memory");
  __syncthreads();

  f32x4 oacc[2][4] = {};
  f32x4 dacc[2] = {};
  const f32x4 cinit = {-C2L2, -C2L2, -C2L2, -C2L2};
  const h8 ones8 = {(f16)1.0f, (f16)1.0f, (f16)1.0f, (f16)1.0f,
                    (f16)1.0f, (f16)1.0f, (f16)1.0f, (f16)1.0f};

  for (int kt = 0; kt < NT64; ++kt) {
    int cur = kt & 1;
    int nxt = (kt + 1) & (NT64 - 1);
    STAGE(cur ^ 1, nxt);

    const f16* kb_ = kbuf[cur];
    const f16* vb_ = vbuf[cur];
#pragma unroll
    for (int sub = 0; sub < 2; ++sub) {
      int sb = sub * 2048;
      h8 kf[2][2];
#pragma unroll
      for (int kb = 0; kb < 2; ++kb)
#pragma unroll
        for (int ch = 0; ch < 2; ++ch) kf[kb][ch] = *(const h8*)&kb_[sb + ek[kb][ch]];
      h8 vv[4];
#pragma unroll
      for (int m = 0; m < 4; ++m) vv[m] = *(const h8*)&vb_[sb + ev + m * 512];

      __builtin_amdgcn_s_setprio(1);
      f32x4 sacc[2][2];
#pragma unroll
      for (int t = 0; t < 2; ++t)
#pragma unroll
        for (int kb = 0; kb < 2; ++kb) {
          sacc[t][kb] = MFMA32(kf[kb][0], qf[t][0], cinit);
          sacc[t][kb] = MFMA32(kf[kb][1], qf[t][1], sacc[t][kb]);
        }
      h8 pf8[2];
#pragma unroll
      for (int t = 0; t < 2; ++t) {
        float e0 = EXP2(sacc[t][0][0]);
        float e1 = EXP2(sacc[t][0][1]);
        float e2 = EXP2(sacc[t][0][2]);
        float e3 = EXP2(sacc[t][0][3]);
        float e4 = EXP2(sacc[t][1][0]);
        float e5 = EXP2(sacc[t][1][1]);
        float e6 = EXP2(sacc[t][1][2]);
        float e7 = EXP2(sacc[t][1][3]);
        fp16x2 p01 = __builtin_amdgcn_cvt_pkrtz(e0, e1);
        fp16x2 p23 = __builtin_amdgcn_cvt_pkrtz(e2, e3);
        fp16x2 p45 = __builtin_amdgcn_cvt_pkrtz(e4, e5);
        fp16x2 p67 = __builtin_amdgcn_cvt_pkrtz(e6, e7);
        fp16x4 lo4 = __builtin_shufflevector(p01, p23, 0, 1, 2, 3);
        fp16x4 hi4 = __builtin_shufflevector(p45, p67, 0, 1, 2, 3);
        fp16x8 p8 = __builtin_shufflevector(lo4, hi4, 0, 1, 2, 3, 4, 5, 6, 7);
        pf8[t] = __builtin_bit_cast(h8, p8);
      }
#pragma unroll
      for (int t = 0; t < 2; ++t) dacc[t] = MFMA32(ones8, pf8[t], dacc[t]);
#pragma unroll
      for (int t = 0; t < 2; ++t)
#pragma unroll
        for (int m = 0; m < 4; ++m) oacc[t][m] = MFMA32(vv[m], pf8[t], oacc[t][m]);
      __builtin_amdgcn_s_setprio(0);
    }
    asm volatile("s_waitcnt vmcnt(0)" ::: "memory");
    __syncthreads();
  }

  int b = bh >> 2, h = bh & 3;
#pragma unroll
  for (int t = 0; t < 2; ++t) {
    float inv = 1.0f / dacc[t][0];  // every lane holds its own q-column's sum
    f16* rp = res + (size_t)(b * SS + q0 + t * 16 + lr) * CC + h * DK + lg * 4;
#pragma unroll
    for (int m = 0; m < 4; ++m) {
      h4 rv;
#pragma unroll
      for (int r = 0; r < 4; ++r) rv[r] = (f16)(oacc[t][m][r] * inv);
      *(h4*)(rp + m * 16) = rv;
    }
  }
}

// ---------------- out GEMM + bias + residual ----------------
__global__ __launch_bounds__(256) void k_out(const f16* __restrict__ res,
                                             const f16* __restrict__ wo,
                                             const float* __restrict__ bo,
                                             const float* __restrict__ x,
                                             float* __restrict__ out) {
  int b = blockIdx.z;
  int c0 = blockIdx.y * 64;
  int w = threadIdx.x >> 6, l = threadIdx.x & 63;
  int s0 = blockIdx.x * 64 + w * 16;
  int lr = l & 15, lg = l >> 4;

  const f16* aptr = res + (size_t)(b * SS + s0 + lr) * CC;
  const f16* bptr = wo + (size_t)(c0 + lr) * CC;
  f32x4 acc[4] = {};
#pragma unroll
  for (int kk = 0; kk < CC; kk += 32) {
    h8 af = *(const h8*)(aptr + kk + lg * 8);
#pragma unroll
    for (int n = 0; n < 4; ++n) {
      h8 bf = *(const h8*)(bptr + n * 16 * CC + kk + lg * 8);
      acc[n] = MFMA32(af, bf, acc[n]);
    }
  }
#pragma unroll
  for (int n = 0; n < 4; ++n) {
    int c = c0 + n * 16 + lr;
    float bb = bo[c];
    const float* xp = x + (size_t)(b * CC + c) * SS + s0 + lg * 4;
    float4 xv = *(const float4*)xp;
    float4 ov;
    ov.x = acc[n][0] + bb + xv.x;
    ov.y = acc[n][1] + bb + xv.y;
    ov.z = acc[n][2] + bb + xv.z;
    ov.w = acc[n][3] + bb + xv.w;
    *(float4*)(out + (size_t)(b * CC + c) * SS + s0 + lg * 4) = ov;
  }
}

extern "C" void kernel_launch(void* const* d_in, const int* in_sizes, int n_in,
                              void* d_out, int out_size, void* d_ws, size_t ws_size,
                              hipStream_t stream) {
  const float* x = (const float*)d_in[0];
  const float* w_proj = (const float*)d_in[1];
  const float* b_proj = (const float*)d_in[2];
  const float* w_out = (const float*)d_in[3];
  const float* b_out = (const float*)d_in[4];
  float* out = (float*)d_out;

  char* p = (char*)d_ws;
  f16* wp = (f16*)p; p += (size_t)O3 * CC * 2;
  f16* wo = (f16*)p; p += (size_t)CC * CC * 2;
  f16* qh = (f16*)p; p += (size_t)BB * HH * SS * DK * 2;
  f16* ksw = (f16*)p; p += (size_t)BB * HH * SS * DK * 2;
  f16* vsw = (f16*)p; p += (size_t)BB * HH * SS * DK * 2;
  f16* res = (f16*)p;

  k_cast2<<<(O3 * CC + CC * CC + 255) / 256, 256, 0, stream>>>(w_proj, wp, O3 * CC,
                                                               w_out, wo, CC * CC);
  k_qkvf<<<dim3(SS / 32, BB), 256, 0, stream>>>(x, wp, b_proj, qh, ksw, vsw);
  k_attn<<<dim3(1024), 128, 0, stream>>>(qh, ksw, vsw, res);
  k_out<<<dim3(SS / 64, CC / 64, BB), 256, 0, stream>>>(res, wo, b_out, x, out);
}

// Round 10
// 137.679 us; speedup vs baseline: 1.1578x; 1.0004x over previous
//
#include <hip/hip_runtime.h>

// AttentionBlock: B=8, C=256, S=2048, H=4, DK=64
// prep(transpose+cast x -> xt, + weight casts) -> QKV GEMM (3072 blocks, high TLP)
// -> fused attention (LDS double-buffered KV, 2-wave blocks, all-K=32 MFMAs)
// -> out GEMM + residual. fp16 storage, fp32 MFMA accum.
// Softmax: constant-shift exp2 (scale*log2e folded into Q, shift folded into MFMA
// C-init), raw v_exp_f32, denominator via ones-row MFMA (permuted-k K=32 PV).

typedef _Float16 f16;
typedef __attribute__((ext_vector_type(4))) float f32x4;
typedef __attribute__((ext_vector_type(8))) _Float16 h8;
typedef __attribute__((ext_vector_type(4))) _Float16 h4;
typedef __attribute__((ext_vector_type(2))) __fp16 fp16x2;
typedef __attribute__((ext_vector_type(4))) __fp16 fp16x4;
typedef __attribute__((ext_vector_type(8))) __fp16 fp16x8;

#define SS 2048
#define CC 256
#define BB 8
#define HH 4
#define DK 64
#define O3 768
#define NT64 32  // 32 tiles of 64 keys; tile = 4096 f16 (8KB) each for K and V
#define C1F 0.1803368801111204f   // 0.125 * log2(e)
#define C2L2 11.541560327111707f  // 8 * log2(e)

#define MFMA32(a, b, c) __builtin_amdgcn_mfma_f32_16x16x32_f16(a, b, c, 0, 0, 0)

#if __has_builtin(__builtin_amdgcn_exp2f)
#define EXP2(x) __builtin_amdgcn_exp2f(x)  // raw v_exp_f32 (args in [-40,-3]: safe)
#else
#define EXP2(x) exp2f(x)
#endif

__device__ __forceinline__ void async_ld16(const f16* g, f16* lds) {
  __builtin_amdgcn_global_load_lds(
      (const __attribute__((address_space(1))) unsigned int*)g,
      (__attribute__((address_space(3))) unsigned int*)lds, 16, 0, 0);
}

// ---------------- prep: xt[b][s][c] = (f16) x[b][c][s]; z==8: weight casts ----------------
__global__ __launch_bounds__(256) void k_prep(const float* __restrict__ x,
                                              f16* __restrict__ xt,
                                              const float* __restrict__ w_proj,
                                              const float* __restrict__ w_out,
                                              f16* __restrict__ wp, f16* __restrict__ wo) {
  if (blockIdx.z == 8) {
    // 128 slices x 2048 elems: cast w_proj (196608) then w_out (65536)
    int slice = blockIdx.y * 32 + blockIdx.x;
    int i0 = slice * 2048 + threadIdx.x * 8;
    const float* src = (i0 < O3 * CC) ? (w_proj + i0) : (w_out + (i0 - O3 * CC));
    f16* dst = (i0 < O3 * CC) ? (wp + i0) : (wo + (i0 - O3 * CC));
    float4 a = *(const float4*)src;
    float4 b = *(const float4*)(src + 4);
    h8 v = {(f16)a.x, (f16)a.y, (f16)a.z, (f16)a.w,
            (f16)b.x, (f16)b.y, (f16)b.z, (f16)b.w};
    *(h8*)dst = v;
    return;
  }
  __shared__ float tile[64][65];
  int b = blockIdx.z, c0 = blockIdx.y * 64, s0 = blockIdx.x * 64;
  int t = threadIdx.x;
#pragma unroll
  for (int it = 0; it < 16; ++it) {
    int idx = it * 256 + t;
    int cl = idx >> 6, sl = idx & 63;
    tile[cl][sl] = x[(size_t)(b * CC + c0 + cl) * SS + s0 + sl];
  }
  __syncthreads();
#pragma unroll
  for (int it = 0; it < 16; ++it) {
    int idx = it * 256 + t;
    int sl = idx >> 6, cl = idx & 63;
    xt[(size_t)(b * SS + s0 + sl) * CC + c0 + cl] = (f16)tile[cl][sl];
  }
}

// ---------------- QKV GEMM (high-TLP: 3072 blocks) ----------------
// Grid (32 s-tiles, 12 o-tiles, 8 b), 256 thr = 4 waves; wave owns 16 s-rows.
//   q: row-major qh[bh][s][d], PRE-SCALED by C1F
//   k: ksw subtile elem = kl*64 + (doff ^ ((kl&7)*8))
//   v: vsw subtile elem = d*32 + (pp^((d>>1)&3))*8 + o*4 + (kl&3)
__global__ __launch_bounds__(256) void k_qkv(const f16* __restrict__ xt,
                                             const f16* __restrict__ wp,
                                             const float* __restrict__ bp,
                                             f16* __restrict__ qh, f16* __restrict__ ksw,
                                             f16* __restrict__ vsw) {
  __shared__ f16 lt[4][16][72];
  int b = blockIdx.z;
  int o0 = blockIdx.y * 64;
  int w = threadIdx.x >> 6, l = threadIdx.x & 63;
  int s0 = blockIdx.x * 64 + w * 16;
  int lr = l & 15, lg = l >> 4;

  const f16* aptr = xt + (size_t)(b * SS + s0 + lr) * CC;
  const f16* bptr = wp + (size_t)(o0 + lr) * CC;
  f32x4 acc[4] = {};
#pragma unroll
  for (int kk = 0; kk < CC; kk += 32) {
    h8 af = *(const h8*)(aptr + kk + lg * 8);
#pragma unroll
    for (int n = 0; n < 4; ++n) {
      h8 bf = *(const h8*)(bptr + n * 16 * CC + kk + lg * 8);
      acc[n] = MFMA32(af, bf, acc[n]);
    }
  }
  int seg = blockIdx.y % 3;  // 0=q 1=k 2=v
  int h = blockIdx.y / 3;
  int bh = b * HH + h;
  float scl = (seg == 0) ? C1F : 1.0f;
#pragma unroll
  for (int n = 0; n < 4; ++n) {
    float bb = bp[o0 + n * 16 + lr];
#pragma unroll
    for (int r = 0; r < 4; ++r) acc[n][r] = (acc[n][r] + bb) * scl;
  }

  if (seg == 2) {
#pragma unroll
    for (int n = 0; n < 4; ++n) {
      int d = n * 16 + lr;
      int sg = s0 + lg * 4;
      int kl = sg & 31;
      int o = kl >> 4;
      int pp = (kl & 15) >> 2;
      int ps = pp ^ ((d >> 1) & 3);
      h4 pv;
#pragma unroll
      for (int r = 0; r < 4; ++r) pv[r] = (f16)acc[n][r];
      size_t elem = ((size_t)bh * NT64 + (sg >> 6)) * 4096 + ((sg >> 5) & 1) * 2048 +
                    d * 32 + ps * 8 + o * 4;
      *(h4*)(vsw + elem) = pv;
    }
  } else {
#pragma unroll
    for (int n = 0; n < 4; ++n)
#pragma unroll
      for (int r = 0; r < 4; ++r) lt[w][lg * 4 + r][n * 16 + lr] = (f16)acc[n][r];
    __syncthreads();
    int srow = l >> 2;
    int key_g = s0 + srow;
    const f16* srcr = &lt[w][srow][(l & 3) * 16];
    if (seg == 0) {
      f16* dst = qh + (size_t)(bh * SS + key_g) * DK + (l & 3) * 16;
      ((int4*)dst)[0] = ((const int4*)srcr)[0];
      ((int4*)dst)[1] = ((const int4*)srcr)[1];
    } else {
      int kl = key_g & 31;
      size_t tb = ((size_t)bh * NT64 + (key_g >> 6)) * 4096 + ((key_g >> 5) & 1) * 2048 +
                  (size_t)kl * 64;
      int swz = (kl & 7) << 3;
      int d0 = (l & 3) * 16;
      *(h8*)(ksw + tb + (d0 ^ swz)) = ((const h8*)srcr)[0];
      *(h8*)(ksw + tb + ((d0 + 8) ^ swz)) = ((const h8*)srcr)[1];
    }
  }
}

// ---------------- attention ----------------
// Block: 2 waves x 32 queries = 64 q; 1024 blocks = 4/CU. 64-key tiles double-buffered
// in LDS (8KB K + 8KB V per buf), staged via global_load_lds w=16, shared by both waves.
// S^T = mfma32(K, Qscaled) with C-init = -8*log2e. P = exp2(sacc) via v_exp_f32.
// PV + denominator as K=32 MFMAs under the permuted-k convention:
//   kslot lg*8+e -> key (e<4 ? lg*4+e : 16+lg*4+e-4); vv[m] 8-group and
//   pf8 = [pf_kb0 | pf_kb1] both follow it, so O^T accumulates correctly.
__global__ __launch_bounds__(128) void k_attn(const f16* __restrict__ qh,
                                              const f16* __restrict__ ksw,
                                              const f16* __restrict__ vsw,
                                              f16* __restrict__ res) {
  __shared__ f16 kbuf[2][4096];
  __shared__ f16 vbuf[2][4096];
  int id = blockIdx.x;
  int xcd = id & 7, slot = id >> 3;  // 128 slots per XCD
  int bh = xcd * 4 + (slot >> 5);    // 4 heads per XCD -> K/V L2-resident
  int qt = slot & 31;
  int w = threadIdx.x >> 6, l = threadIdx.x & 63;
  int q0 = qt * 64 + w * 32;
  int lr = l & 15, lg = l >> 4;

  h8 qf[2][2];
#pragma unroll
  for (int t = 0; t < 2; ++t) {
    const f16* qp = qh + (size_t)(bh * SS + q0 + t * 16 + lr) * DK;
    qf[t][0] = *(const h8*)(qp + lg * 8);
    qf[t][1] = *(const h8*)(qp + 32 + lg * 8);
  }

  const f16* kg = ksw + (size_t)bh * (SS * DK);
  const f16* vg = vsw + (size_t)bh * (SS * DK);

#define STAGE(bufi, tile)                                           \
  {                                                                 \
    const f16* kq = kg + (size_t)(tile) * 4096 + w * 2048 + l * 8;  \
    const f16* vq = vg + (size_t)(tile) * 4096 + w * 2048 + l * 8;  \
    f16* kd = &kbuf[bufi][w * 2048];                                \
    f16* vd = &vbuf[bufi][w * 2048];                                \
    async_ld16(kq, kd);                                             \
    async_ld16(kq + 512, kd + 512);                                 \
    async_ld16(kq + 1024, kd + 1024);                               \
    async_ld16(kq + 1536, kd + 1536);                               \
    async_ld16(vq, vd);                                             \
    async_ld16(vq + 512, vd + 512);                                 \
    async_ld16(vq + 1024, vd + 1024);                               \
    async_ld16(vq + 1536, vd + 1536);                               \
  }

  // fragment element offsets within a 2048-elem subtile
  int swk = (lr & 7) << 3;
  int ek[2][2];
#pragma unroll
  for (int kb = 0; kb < 2; ++kb)
#pragma unroll
    for (int ch = 0; ch < 2; ++ch)
      ek[kb][ch] = (lr + kb * 16) * 64 + ((ch * 32 + lg * 8) ^ swk);
  int ev = lr * 32 + ((lg ^ ((lr >> 1) & 3)) * 8);  // + m*512

  STAGE(0, 0);
  asm volatile("s_waitcnt vmcnt(0)" ::: "memory");
  __syncthreads();

  f32x4 oacc[2][4] = {};
  f32x4 dacc[2] = {};
  const f32x4 cinit = {-C2L2, -C2L2, -C2L2, -C2L2};
  const h8 ones8 = {(f16)1.0f, (f16)1.0f, (f16)1.0f, (f16)1.0f,
                    (f16)1.0f, (f16)1.0f, (f16)1.0f, (f16)1.0f};

  for (int kt = 0; kt < NT64; ++kt) {
    int cur = kt & 1;
    int nxt = (kt + 1) & (NT64 - 1);
    STAGE(cur ^ 1, nxt);

    const f16* kb_ = kbuf[cur];
    const f16* vb_ = vbuf[cur];
#pragma unroll
    for (int sub = 0; sub < 2; ++sub) {
      int sb = sub * 2048;
      h8 kf[2][2];
#pragma unroll
      for (int kb = 0; kb < 2; ++kb)
#pragma unroll
        for (int ch = 0; ch < 2; ++ch) kf[kb][ch] = *(const h8*)&kb_[sb + ek[kb][ch]];
      h8 vv[4];
#pragma unroll
      for (int m = 0; m < 4; ++m) vv[m] = *(const h8*)&vb_[sb + ev + m * 512];

      __builtin_amdgcn_s_setprio(1);
      f32x4 sacc[2][2];
#pragma unroll
      for (int t = 0; t < 2; ++t)
#pragma unroll
        for (int kb = 0; kb < 2; ++kb) {
          sacc[t][kb] = MFMA32(kf[kb][0], qf[t][0], cinit);
          sacc[t][kb] = MFMA32(kf[kb][1], qf[t][1], sacc[t][kb]);
        }
      h8 pf8[2];
#pragma unroll
      for (int t = 0; t < 2; ++t) {
        float e0 = EXP2(sacc[t][0][0]);
        float e1 = EXP2(sacc[t][0][1]);
        float e2 = EXP2(sacc[t][0][2]);
        float e3 = EXP2(sacc[t][0][3]);
        float e4 = EXP2(sacc[t][1][0]);
        float e5 = EXP2(sacc[t][1][1]);
        float e6 = EXP2(sacc[t][1][2]);
        float e7 = EXP2(sacc[t][1][3]);
        fp16x2 p01 = __builtin_amdgcn_cvt_pkrtz(e0, e1);
        fp16x2 p23 = __builtin_amdgcn_cvt_pkrtz(e2, e3);
        fp16x2 p45 = __builtin_amdgcn_cvt_pkrtz(e4, e5);
        fp16x2 p67 = __builtin_amdgcn_cvt_pkrtz(e6, e7);
        fp16x4 lo4 = __builtin_shufflevector(p01, p23, 0, 1, 2, 3);
        fp16x4 hi4 = __builtin_shufflevector(p45, p67, 0, 1, 2, 3);
        fp16x8 p8 = __builtin_shufflevector(lo4, hi4, 0, 1, 2, 3, 4, 5, 6, 7);
        pf8[t] = __builtin_bit_cast(h8, p8);
      }
#pragma unroll
      for (int t = 0; t < 2; ++t) dacc[t] = MFMA32(ones8, pf8[t], dacc[t]);
#pragma unroll
      for (int t = 0; t < 2; ++t)
#pragma unroll
        for (int m = 0; m < 4; ++m) oacc[t][m] = MFMA32(vv[m], pf8[t], oacc[t][m]);
      __builtin_amdgcn_s_setprio(0);
    }
    asm volatile("s_waitcnt vmcnt(0)" ::: "memory");
    __syncthreads();
  }

  int b = bh >> 2, h = bh & 3;
#pragma unroll
  for (int t = 0; t < 2; ++t) {
    float inv = 1.0f / dacc[t][0];  // every lane holds its own q-column's sum
    f16* rp = res + (size_t)(b * SS + q0 + t * 16 + lr) * CC + h * DK + lg * 4;
#pragma unroll
    for (int m = 0; m < 4; ++m) {
      h4 rv;
#pragma unroll
      for (int r = 0; r < 4; ++r) rv[r] = (f16)(oacc[t][m][r] * inv);
      *(h4*)(rp + m * 16) = rv;
    }
  }
}

// ---------------- out GEMM + bias + residual ----------------
__global__ __launch_bounds__(256) void k_out(const f16* __restrict__ res,
                                             const f16* __restrict__ wo,
                                             const float* __restrict__ bo,
                                             const float* __restrict__ x,
                                             float* __restrict__ out) {
  int b = blockIdx.z;
  int c0 = blockIdx.y * 64;
  int w = threadIdx.x >> 6, l = threadIdx.x & 63;
  int s0 = blockIdx.x * 64 + w * 16;
  int lr = l & 15, lg = l >> 4;

  const f16* aptr = res + (size_t)(b * SS + s0 + lr) * CC;
  const f16* bptr = wo + (size_t)(c0 + lr) * CC;
  f32x4 acc[4] = {};
#pragma unroll
  for (int kk = 0; kk < CC; kk += 32) {
    h8 af = *(const h8*)(aptr + kk + lg * 8);
#pragma unroll
    for (int n = 0; n < 4; ++n) {
      h8 bf = *(const h8*)(bptr + n * 16 * CC + kk + lg * 8);
      acc[n] = MFMA32(af, bf, acc[n]);
    }
  }
#pragma unroll
  for (int n = 0; n < 4; ++n) {
    int c = c0 + n * 16 + lr;
    float bb = bo[c];
    const float* xp = x + (size_t)(b * CC + c) * SS + s0 + lg * 4;
    float4 xv = *(const float4*)xp;
    float4 ov;
    ov.x = acc[n][0] + bb + xv.x;
    ov.y = acc[n][1] + bb + xv.y;
    ov.z = acc[n][2] + bb + xv.z;
    ov.w = acc[n][3] + bb + xv.w;
    *(float4*)(out + (size_t)(b * CC + c) * SS + s0 + lg * 4) = ov;
  }
}

extern "C" void kernel_launch(void* const* d_in, const int* in_sizes, int n_in,
                              void* d_out, int out_size, void* d_ws, size_t ws_size,
                              hipStream_t stream) {
  const float* x = (const float*)d_in[0];
  const float* w_proj = (const float*)d_in[1];
  const float* b_proj = (const float*)d_in[2];
  const float* w_out = (const float*)d_in[3];
  const float* b_out = (const float*)d_in[4];
  float* out = (float*)d_out;

  char* p = (char*)d_ws;
  f16* xt = (f16*)p; p += (size_t)BB * SS * CC * 2;
  f16* wp = (f16*)p; p += (size_t)O3 * CC * 2;
  f16* wo = (f16*)p; p += (size_t)CC * CC * 2;
  f16* qh = (f16*)p; p += (size_t)BB * HH * SS * DK * 2;
  f16* ksw = (f16*)p; p += (size_t)BB * HH * SS * DK * 2;
  f16* vsw = (f16*)p; p += (size_t)BB * HH * SS * DK * 2;
  f16* res = (f16*)p;

  k_prep<<<dim3(SS / 64, CC / 64, BB + 1), 256, 0, stream>>>(x, xt, w_proj, w_out, wp, wo);
  k_qkv<<<dim3(SS / 64, O3 / 64, BB), 256, 0, stream>>>(xt, wp, b_proj, qh, ksw, vsw);
  k_attn<<<dim3(1024), 128, 0, stream>>>(qh, ksw, vsw, res);
  k_out<<<dim3(SS / 64, CC / 64, BB), 256, 0, stream>>>(res, wo, b_out, x, out);
}

// Round 11
// 101.573 us; speedup vs baseline: 1.5693x; 1.3555x over previous
//
#include <hip/hip_runtime.h>

// AttentionBlock: B=8, C=256, S=2048, H=4, DK=64
// k_prep (transpose+cast x -> xt [chunk-swizzled], weight casts; wp chunk-swizzled)
// -> k_qkv (LDS-staged A/B via global_load_lds, LDS-repacked coalesced outputs)
// -> k_attn (LDS double-buffered KV, 2-wave blocks, all-K=32 MFMAs)
// -> k_out (GEMM + bias + residual). fp16 storage, fp32 MFMA accum.
// Softmax: constant-shift exp2 (scale*log2e folded into Q, shift in MFMA C-init),
// raw v_exp_f32, denominator via ones-row MFMA (permuted-k K=32 PV).
// Swizzle convention: row-major rows of 256 f16 = 32 16B-chunks; chunk ch of row r
// is stored at position ch ^ (r&7). ds_read_b128 frag reads then spread 16 lanes
// across 8 bank-quads (2-way = free).

typedef _Float16 f16;
typedef __attribute__((ext_vector_type(4))) float f32x4;
typedef __attribute__((ext_vector_type(8))) _Float16 h8;
typedef __attribute__((ext_vector_type(4))) _Float16 h4;
typedef __attribute__((ext_vector_type(2))) __fp16 fp16x2;
typedef __attribute__((ext_vector_type(4))) __fp16 fp16x4;
typedef __attribute__((ext_vector_type(8))) __fp16 fp16x8;

#define SS 2048
#define CC 256
#define BB 8
#define HH 4
#define DK 64
#define O3 768
#define NT64 32  // 32 tiles of 64 keys; tile = 4096 f16 (8KB) each for K and V
#define C1F 0.1803368801111204f   // 0.125 * log2(e)
#define C2L2 11.541560327111707f  // 8 * log2(e)

#define MFMA32(a, b, c) __builtin_amdgcn_mfma_f32_16x16x32_f16(a, b, c, 0, 0, 0)

#if __has_builtin(__builtin_amdgcn_exp2f)
#define EXP2(x) __builtin_amdgcn_exp2f(x)  // raw v_exp_f32 (args in [-40,-3]: safe)
#else
#define EXP2(x) exp2f(x)
#endif

__device__ __forceinline__ void async_ld16(const f16* g, f16* lds) {
  __builtin_amdgcn_global_load_lds(
      (const __attribute__((address_space(1))) unsigned int*)g,
      (__attribute__((address_space(3))) unsigned int*)lds, 16, 0, 0);
}

// ---------------- prep ----------------
// z<8 : xt[b][s][swizzled c] = (f16) x[b][c][s]
// z==8: weight casts; wp rows chunk-swizzled, wo plain (k_out reads it directly)
__global__ __launch_bounds__(256) void k_prep(const float* __restrict__ x,
                                              f16* __restrict__ xt,
                                              const float* __restrict__ w_proj,
                                              const float* __restrict__ w_out,
                                              f16* __restrict__ wp, f16* __restrict__ wo) {
  if (blockIdx.z == 8) {
    int slice = blockIdx.y * 32 + blockIdx.x;  // 0..127
    int i0 = slice * 2048 + threadIdx.x * 8;
    const float* src;
    f16* dst;
    if (i0 < O3 * CC) {
      src = w_proj + i0;
      int row = i0 >> 8, ch = (i0 & 255) >> 3;
      dst = wp + row * 256 + ((ch ^ (row & 7)) << 3);
    } else {
      int j = i0 - O3 * CC;
      src = w_out + j;
      dst = wo + j;
    }
    float4 a = *(const float4*)src;
    float4 b = *(const float4*)(src + 4);
    h8 v = {(f16)a.x, (f16)a.y, (f16)a.z, (f16)a.w,
            (f16)b.x, (f16)b.y, (f16)b.z, (f16)b.w};
    *(h8*)dst = v;
    return;
  }
  __shared__ float tile[64][65];
  int b = blockIdx.z, c0 = blockIdx.y * 64, s0 = blockIdx.x * 64;
  int t = threadIdx.x;
#pragma unroll
  for (int it = 0; it < 16; ++it) {
    int idx = it * 256 + t;
    int cl = idx >> 6, sl = idx & 63;
    tile[cl][sl] = x[(size_t)(b * CC + c0 + cl) * SS + s0 + sl];
  }
  __syncthreads();
  // 512 chunk-stores (64 s x 8 chunks), 2 per thread; 16B each, swizzled position
#pragma unroll
  for (int cid = t; cid < 512; cid += 256) {
    int sl = cid >> 3, chl = cid & 7;
    int s = s0 + sl;
    int gch = (c0 >> 3) + chl;
    h8 v;
#pragma unroll
    for (int e = 0; e < 8; ++e) v[e] = (f16)tile[chl * 8 + e][sl];
    *(h8*)(xt + (size_t)(b * SS + s) * CC + ((gch ^ (s & 7)) << 3)) = v;
  }
}

// ---------------- QKV GEMM (LDS-staged, coalesced in AND out) ----------------
// Grid (32 s-tiles, 12 o-tiles, 8 b) = 3072 blocks, 4 waves; LDS 72KB -> 2 blocks/CU.
// Stage A (xt rows, swizzled) + B (wp rows, swizzled) via 16B global_load_lds,
// frag ds_read_b128 with chunk-XOR; epilogue repacks D into Ot at the TARGET layout
// (qh row-major / ksw / vsw subtile formats), then 8KB coalesced dump.
__global__ __launch_bounds__(256) void k_qkv(const f16* __restrict__ xt,
                                             const f16* __restrict__ wp,
                                             const float* __restrict__ bp,
                                             f16* __restrict__ qh, f16* __restrict__ ksw,
                                             f16* __restrict__ vsw) {
  __shared__ f16 As[16384];  // 64 x 256 (32KB)
  __shared__ f16 Bs[16384];  // 64 x 256 (32KB)
  __shared__ f16 Ot[4096];   // 8KB out staging
  int b = blockIdx.z;
  int oti = blockIdx.y, o0 = oti * 64;
  int s0 = blockIdx.x * 64;
  int w = threadIdx.x >> 6, l = threadIdx.x & 63;
  int lr = l & 15, lg = l >> 4;

  const f16* Ag = xt + ((size_t)b * SS + s0) * CC;  // 32KB contiguous
  const f16* Bg = wp + (size_t)o0 * CC;
#pragma unroll
  for (int i = 0; i < 8; ++i) {
    int off = w * 4096 + i * 512;
    async_ld16(Ag + off + l * 8, &As[off]);
    async_ld16(Bg + off + l * 8, &Bs[off]);
  }
  asm volatile("s_waitcnt vmcnt(0)" ::: "memory");
  __syncthreads();

  f32x4 acc[4] = {};
#pragma unroll
  for (int kk = 0; kk < CC; kk += 32) {
    int chs = (((kk >> 3) + lg) ^ (lr & 7)) << 3;
    h8 af = *(const h8*)&As[(w * 16 + lr) * 256 + chs];
#pragma unroll
    for (int n = 0; n < 4; ++n) {
      h8 bf = *(const h8*)&Bs[(n * 16 + lr) * 256 + chs];
      acc[n] = MFMA32(af, bf, acc[n]);
    }
  }

  int seg = oti % 3;  // 0=q 1=k 2=v
  int h = oti / 3;
  int bh = b * HH + h;
  float scl = (seg == 0) ? C1F : 1.0f;
#pragma unroll
  for (int n = 0; n < 4; ++n) {
    float bb = bp[o0 + n * 16 + lr];
#pragma unroll
    for (int r = 0; r < 4; ++r) acc[n][r] = (acc[n][r] + bb) * scl;
  }

  // repack D into Ot at target layout (wave-disjoint addresses, no barrier needed yet)
  if (seg == 2) {
#pragma unroll
    for (int n = 0; n < 4; ++n) {
      int d = n * 16 + lr;
#pragma unroll
      for (int r = 0; r < 4; ++r) {
        int sl = w * 16 + lg * 4 + r;
        int kl = sl & 31;
        int ps = ((kl & 15) >> 2) ^ ((d >> 1) & 3);
        Ot[(sl >> 5) * 2048 + d * 32 + ps * 8 + ((kl >> 4) << 2) + (kl & 3)] =
            (f16)acc[n][r];
      }
    }
  } else if (seg == 1) {
#pragma unroll
    for (int n = 0; n < 4; ++n) {
      int d = n * 16 + lr;
#pragma unroll
      for (int r = 0; r < 4; ++r) {
        int sl = w * 16 + lg * 4 + r;
        int kl = sl & 31;
        Ot[(sl >> 5) * 2048 + kl * 64 + (((d >> 3) ^ (kl & 7)) << 3) + (d & 7)] =
            (f16)acc[n][r];
      }
    }
  } else {
#pragma unroll
    for (int n = 0; n < 4; ++n)
#pragma unroll
      for (int r = 0; r < 4; ++r)
        Ot[(w * 16 + lg * 4 + r) * 64 + n * 16 + lr] = (f16)acc[n][r];
  }
  __syncthreads();

  int t = threadIdx.x;
  f16* dst;
  if (seg == 0)
    dst = qh + ((size_t)bh * SS + s0) * DK;
  else if (seg == 1)
    dst = ksw + ((size_t)bh * NT64 + (s0 >> 6)) * 4096;
  else
    dst = vsw + ((size_t)bh * NT64 + (s0 >> 6)) * 4096;
  *(int4*)(dst + t * 16) = *(const int4*)&Ot[t * 16];
  *(int4*)(dst + t * 16 + 8) = *(const int4*)&Ot[t * 16 + 8];
}

// ---------------- attention (unchanged from round 9) ----------------
__global__ __launch_bounds__(128) void k_attn(const f16* __restrict__ qh,
                                              const f16* __restrict__ ksw,
                                              const f16* __restrict__ vsw,
                                              f16* __restrict__ res) {
  __shared__ f16 kbuf[2][4096];
  __shared__ f16 vbuf[2][4096];
  int id = blockIdx.x;
  int xcd = id & 7, slot = id >> 3;  // 128 slots per XCD
  int bh = xcd * 4 + (slot >> 5);    // 4 heads per XCD -> K/V L2-resident
  int qt = slot & 31;
  int w = threadIdx.x >> 6, l = threadIdx.x & 63;
  int q0 = qt * 64 + w * 32;
  int lr = l & 15, lg = l >> 4;

  h8 qf[2][2];
#pragma unroll
  for (int t = 0; t < 2; ++t) {
    const f16* qp = qh + (size_t)(bh * SS + q0 + t * 16 + lr) * DK;
    qf[t][0] = *(const h8*)(qp + lg * 8);
    qf[t][1] = *(const h8*)(qp + 32 + lg * 8);
  }

  const f16* kg = ksw + (size_t)bh * (SS * DK);
  const f16* vg = vsw + (size_t)bh * (SS * DK);

#define STAGE(bufi, tile)                                           \
  {                                                                 \
    const f16* kq = kg + (size_t)(tile) * 4096 + w * 2048 + l * 8;  \
    const f16* vq = vg + (size_t)(tile) * 4096 + w * 2048 + l * 8;  \
    f16* kd = &kbuf[bufi][w * 2048];                                \
    f16* vd = &vbuf[bufi][w * 2048];                                \
    async_ld16(kq, kd);                                             \
    async_ld16(kq + 512, kd + 512);                                 \
    async_ld16(kq + 1024, kd + 1024);                               \
    async_ld16(kq + 1536, kd + 1536);                               \
    async_ld16(vq, vd);                                             \
    async_ld16(vq + 512, vd + 512);                                 \
    async_ld16(vq + 1024, vd + 1024);                               \
    async_ld16(vq + 1536, vd + 1536);                               \
  }

  int swk = (lr & 7) << 3;
  int ek[2][2];
#pragma unroll
  for (int kb = 0; kb < 2; ++kb)
#pragma unroll
    for (int ch = 0; ch < 2; ++ch)
      ek[kb][ch] = (lr + kb * 16) * 64 + ((ch * 32 + lg * 8) ^ swk);
  int ev = lr * 32 + ((lg ^ ((lr >> 1) & 3)) * 8);  // + m*512

  STAGE(0, 0);
  asm volatile("s_waitcnt vmcnt(0)" ::: "memory");
  __syncthreads();

  f32x4 oacc[2][4] = {};
  f32x4 dacc[2] = {};
  const f32x4 cinit = {-C2L2, -C2L2, -C2L2, -C2L2};
  const h8 ones8 = {(f16)1.0f, (f16)1.0f, (f16)1.0f, (f16)1.0f,
                    (f16)1.0f, (f16)1.0f, (f16)1.0f, (f16)1.0f};

  for (int kt = 0; kt < NT64; ++kt) {
    int cur = kt & 1;
    int nxt = (kt + 1) & (NT64 - 1);
    STAGE(cur ^ 1, nxt);

    const f16* kb_ = kbuf[cur];
    const f16* vb_ = vbuf[cur];
#pragma unroll
    for (int sub = 0; sub < 2; ++sub) {
      int sb = sub * 2048;
      h8 kf[2][2];
#pragma unroll
      for (int kb = 0; kb < 2; ++kb)
#pragma unroll
        for (int ch = 0; ch < 2; ++ch) kf[kb][ch] = *(const h8*)&kb_[sb + ek[kb][ch]];
      h8 vv[4];
#pragma unroll
      for (int m = 0; m < 4; ++m) vv[m] = *(const h8*)&vb_[sb + ev + m * 512];

      __builtin_amdgcn_s_setprio(1);
      f32x4 sacc[2][2];
#pragma unroll
      for (int t = 0; t < 2; ++t)
#pragma unroll
        for (int kb = 0; kb < 2; ++kb) {
          sacc[t][kb] = MFMA32(kf[kb][0], qf[t][0], cinit);
          sacc[t][kb] = MFMA32(kf[kb][1], qf[t][1], sacc[t][kb]);
        }
      h8 pf8[2];
#pragma unroll
      for (int t = 0; t < 2; ++t) {
        float e0 = EXP2(sacc[t][0][0]);
        float e1 = EXP2(sacc[t][0][1]);
        float e2 = EXP2(sacc[t][0][2]);
        float e3 = EXP2(sacc[t][0][3]);
        float e4 = EXP2(sacc[t][1][0]);
        float e5 = EXP2(sacc[t][1][1]);
        float e6 = EXP2(sacc[t][1][2]);
        float e7 = EXP2(sacc[t][1][3]);
        fp16x2 p01 = __builtin_amdgcn_cvt_pkrtz(e0, e1);
        fp16x2 p23 = __builtin_amdgcn_cvt_pkrtz(e2, e3);
        fp16x2 p45 = __builtin_amdgcn_cvt_pkrtz(e4, e5);
        fp16x2 p67 = __builtin_amdgcn_cvt_pkrtz(e6, e7);
        fp16x4 lo4 = __builtin_shufflevector(p01, p23, 0, 1, 2, 3);
        fp16x4 hi4 = __builtin_shufflevector(p45, p67, 0, 1, 2, 3);
        fp16x8 p8 = __builtin_shufflevector(lo4, hi4, 0, 1, 2, 3, 4, 5, 6, 7);
        pf8[t] = __builtin_bit_cast(h8, p8);
      }
#pragma unroll
      for (int t = 0; t < 2; ++t) dacc[t] = MFMA32(ones8, pf8[t], dacc[t]);
#pragma unroll
      for (int t = 0; t < 2; ++t)
#pragma unroll
        for (int m = 0; m < 4; ++m) oacc[t][m] = MFMA32(vv[m], pf8[t], oacc[t][m]);
      __builtin_amdgcn_s_setprio(0);
    }
    asm volatile("s_waitcnt vmcnt(0)" ::: "memory");
    __syncthreads();
  }

  int b = bh >> 2, h = bh & 3;
#pragma unroll
  for (int t = 0; t < 2; ++t) {
    float inv = 1.0f / dacc[t][0];  // every lane holds its own q-column's sum
    f16* rp = res + (size_t)(b * SS + q0 + t * 16 + lr) * CC + h * DK + lg * 4;
#pragma unroll
    for (int m = 0; m < 4; ++m) {
      h4 rv;
#pragma unroll
      for (int r = 0; r < 4; ++r) rv[r] = (f16)(oacc[t][m][r] * inv);
      *(h4*)(rp + m * 16) = rv;
    }
  }
}

// ---------------- out GEMM + bias + residual (unchanged) ----------------
__global__ __launch_bounds__(256) void k_out(const f16* __restrict__ res,
                                             const f16* __restrict__ wo,
                                             const float* __restrict__ bo,
                                             const float* __restrict__ x,
                                             float* __restrict__ out) {
  int b = blockIdx.z;
  int c0 = blockIdx.y * 64;
  int w = threadIdx.x >> 6, l = threadIdx.x & 63;
  int s0 = blockIdx.x * 64 + w * 16;
  int lr = l & 15, lg = l >> 4;

  const f16* aptr = res + (size_t)(b * SS + s0 + lr) * CC;
  const f16* bptr = wo + (size_t)(c0 + lr) * CC;
  f32x4 acc[4] = {};
#pragma unroll
  for (int kk = 0; kk < CC; kk += 32) {
    h8 af = *(const h8*)(aptr + kk + lg * 8);
#pragma unroll
    for (int n = 0; n < 4; ++n) {
      h8 bf = *(const h8*)(bptr + n * 16 * CC + kk + lg * 8);
      acc[n] = MFMA32(af, bf, acc[n]);
    }
  }
#pragma unroll
  for (int n = 0; n < 4; ++n) {
    int c = c0 + n * 16 + lr;
    float bb = bo[c];
    const float* xp = x + (size_t)(b * CC + c) * SS + s0 + lg * 4;
    float4 xv = *(const float4*)xp;
    float4 ov;
    ov.x = acc[n][0] + bb + xv.x;
    ov.y = acc[n][1] + bb + xv.y;
    ov.z = acc[n][2] + bb + xv.z;
    ov.w = acc[n][3] + bb + xv.w;
    *(float4*)(out + (size_t)(b * CC + c) * SS + s0 + lg * 4) = ov;
  }
}

extern "C" void kernel_launch(void* const* d_in, const int* in_sizes, int n_in,
                              void* d_out, int out_size, void* d_ws, size_t ws_size,
                              hipStream_t stream) {
  const float* x = (const float*)d_in[0];
  const float* w_proj = (const float*)d_in[1];
  const float* b_proj = (const float*)d_in[2];
  const float* w_out = (const float*)d_in[3];
  const float* b_out = (const float*)d_in[4];
  float* out = (float*)d_out;

  char* p = (char*)d_ws;
  f16* xt = (f16*)p; p += (size_t)BB * SS * CC * 2;
  f16* wp = (f16*)p; p += (size_t)O3 * CC * 2;
  f16* wo = (f16*)p; p += (size_t)CC * CC * 2;
  f16* qh = (f16*)p; p += (size_t)BB * HH * SS * DK * 2;
  f16* ksw = (f16*)p; p += (size_t)BB * HH * SS * DK * 2;
  f16* vsw = (f16*)p; p += (size_t)BB * HH * SS * DK * 2;
  f16* res = (f16*)p;

  k_prep<<<dim3(SS / 64, CC / 64, BB + 1), 256, 0, stream>>>(x, xt, w_proj, w_out, wp, wo);
  k_qkv<<<dim3(SS / 64, O3 / 64, BB), 256, 0, stream>>>(xt, wp, b_proj, qh, ksw, vsw);
  k_attn<<<dim3(1024), 128, 0, stream>>>(qh, ksw, vsw, res);
  k_out<<<dim3(SS / 64, CC / 64, BB), 256, 0, stream>>>(res, wo, b_out, x, out);
}